// Round 2
// baseline (331.776 us; speedup 1.0000x reference)
//
#include <hip/hip_runtime.h>
#include <hip/hip_bf16.h>

// Problem constants
#define LD 512
#define LS 2048
#define CS 384
#define CH 16
#define NH 12
#define PQ 4
#define PV 8
#define QCW 336   // packed [q(192) | qp(144)] row width
#define KVW 816   // packed [kv(384) | kvp(432)] row width

typedef __bf16 bf16x8 __attribute__((ext_vector_type(8)));
typedef float  f32x4  __attribute__((ext_vector_type(4)));

// ---------------------------------------------------------------------------
// Split an 8-float run into bf16 hi/lo fragments (hi + lo ~= fp32 value).
// ---------------------------------------------------------------------------
__device__ inline void split_frag(const float* __restrict__ p, bf16x8& hi, bf16x8& lo)
{
    float4 x = *(const float4*)p;
    float4 y = *(const float4*)(p + 4);
    float f[8] = {x.x, x.y, x.z, x.w, y.x, y.y, y.z, y.w};
#pragma unroll
    for (int e = 0; e < 8; ++e) {
        __bf16 h = (__bf16)f[e];
        hi[e] = h;
        lo[e] = (__bf16)(f[e] - (float)h);
    }
}

// ---------------------------------------------------------------------------
// Weight transpose: src[R][Cc] -> dst[Cc][R]. 32x32 LDS tile, 256 threads.
// ---------------------------------------------------------------------------
__global__ __launch_bounds__(256) void transpose_w_kernel(
    const float* __restrict__ src, float* __restrict__ dst, int R, int Cc)
{
    __shared__ float tile[32][33];
    const int r0 = blockIdx.x * 32, c0 = blockIdx.y * 32;
    const int tx = threadIdx.x & 31, ty = threadIdx.x >> 5;  // ty 0..7
#pragma unroll
    for (int rr = 0; rr < 32; rr += 8) {
        int r = r0 + ty + rr, c = c0 + tx;
        tile[ty + rr][tx] = (r < R && c < Cc) ? src[(size_t)r * Cc + c] : 0.f;
    }
    __syncthreads();
#pragma unroll
    for (int rr = 0; rr < 32; rr += 8) {
        int c = c0 + ty + rr, r = r0 + tx;
        if (c < Cc && r < R) dst[(size_t)c * R + r] = tile[tx][ty + rr];
    }
}

// ---------------------------------------------------------------------------
// MFMA GEMM, split-bf16 3-pass: C[M][N] = A[M][K] @ Bt[N][K]^T (+bias).
// ---------------------------------------------------------------------------
__global__ __launch_bounds__(64) void mfma_gemm_bt_kernel(
    const float* __restrict__ A, const float* __restrict__ Bt,
    const float* __restrict__ bias, float* __restrict__ C,
    int M, int N, int K)
{
    const int m0 = blockIdx.x * 32;
    const int n0 = blockIdx.y * 32;
    const int lane = threadIdx.x;
    const int row16 = lane & 15, kq = lane >> 4;

    const float* ap0 = A + (size_t)(m0 + row16) * K + kq * 8;
    const float* ap1 = ap0 + (size_t)16 * K;
    const float* bp0 = Bt + (size_t)(n0 + row16) * K + kq * 8;
    const float* bp1 = bp0 + (size_t)16 * K;
    const bool n1ok = (n0 + 16) < N;

    f32x4 acc00 = {0.f, 0.f, 0.f, 0.f};
    f32x4 acc10 = {0.f, 0.f, 0.f, 0.f};
    f32x4 acc01 = {0.f, 0.f, 0.f, 0.f};
    f32x4 acc11 = {0.f, 0.f, 0.f, 0.f};

    for (int k = 0; k < K; k += 32) {
        bf16x8 a0h, a0l, a1h, a1l, b0h, b0l, b1h, b1l;
        split_frag(ap0 + k, a0h, a0l);
        split_frag(ap1 + k, a1h, a1l);
        split_frag(bp0 + k, b0h, b0l);
        acc00 = __builtin_amdgcn_mfma_f32_16x16x32_bf16(a0h, b0h, acc00, 0, 0, 0);
        acc00 = __builtin_amdgcn_mfma_f32_16x16x32_bf16(a0h, b0l, acc00, 0, 0, 0);
        acc00 = __builtin_amdgcn_mfma_f32_16x16x32_bf16(a0l, b0h, acc00, 0, 0, 0);
        acc10 = __builtin_amdgcn_mfma_f32_16x16x32_bf16(a1h, b0h, acc10, 0, 0, 0);
        acc10 = __builtin_amdgcn_mfma_f32_16x16x32_bf16(a1h, b0l, acc10, 0, 0, 0);
        acc10 = __builtin_amdgcn_mfma_f32_16x16x32_bf16(a1l, b0h, acc10, 0, 0, 0);
        if (n1ok) {
            split_frag(bp1 + k, b1h, b1l);
            acc01 = __builtin_amdgcn_mfma_f32_16x16x32_bf16(a0h, b1h, acc01, 0, 0, 0);
            acc01 = __builtin_amdgcn_mfma_f32_16x16x32_bf16(a0h, b1l, acc01, 0, 0, 0);
            acc01 = __builtin_amdgcn_mfma_f32_16x16x32_bf16(a0l, b1h, acc01, 0, 0, 0);
            acc11 = __builtin_amdgcn_mfma_f32_16x16x32_bf16(a1h, b1h, acc11, 0, 0, 0);
            acc11 = __builtin_amdgcn_mfma_f32_16x16x32_bf16(a1h, b1l, acc11, 0, 0, 0);
            acc11 = __builtin_amdgcn_mfma_f32_16x16x32_bf16(a1l, b1h, acc11, 0, 0, 0);
        }
    }

    const float bv0 = bias ? bias[n0 + row16] : 0.f;
    const float bv1 = (bias && n1ok) ? bias[n0 + 16 + row16] : 0.f;
#pragma unroll
    for (int r = 0; r < 4; ++r) {
        const int mA = m0 + kq * 4 + r;
        const int mB = mA + 16;
        C[(size_t)mA * N + n0 + row16] = acc00[r] + bv0;
        C[(size_t)mB * N + n0 + row16] = acc10[r] + bv0;
        if (n1ok) {
            C[(size_t)mA * N + n0 + 16 + row16] = acc01[r] + bv1;
            C[(size_t)mB * N + n0 + 16 + row16] = acc11[r] + bv1;
        }
    }
}

// ---------------------------------------------------------------------------
// Rotate dst query points (reads packed qcat, qp part at offset 192)
// qp_rot layout: [i][p*3+ax] with p = h*4+pq  (matches kpT row indexing)
// ---------------------------------------------------------------------------
__global__ __launch_bounds__(64) void rot_dst_kernel(
    const float* __restrict__ qcat, const float* __restrict__ Rd,
    const float* __restrict__ td, float* __restrict__ qp_rot,
    float* __restrict__ sqq)
{
    const int i = blockIdx.x, t = threadIdx.x;
    __shared__ float part[48];
    if (t < 48) {
        float x = qcat[i * QCW + 192 + t];
        float y = qcat[i * QCW + 192 + 48 + t];
        float z = qcat[i * QCW + 192 + 96 + t];
        const float* R = Rd + i * 9;
        float rx = R[0] * x + R[1] * y + R[2] * z + td[i * 3 + 0];
        float ry = R[3] * x + R[4] * y + R[5] * z + td[i * 3 + 1];
        float rz = R[6] * x + R[7] * y + R[8] * z + td[i * 3 + 2];
        qp_rot[i * 144 + t * 3 + 0] = rx;
        qp_rot[i * 144 + t * 3 + 1] = ry;
        qp_rot[i * 144 + t * 3 + 2] = rz;
        part[t] = rx * rx + ry * ry + rz * rz;
    }
    __syncthreads();
    if (t < NH) sqq[i * NH + t] = part[t * 4] + part[t * 4 + 1] + part[t * 4 + 2] + part[t * 4 + 3];
}

// ---------------------------------------------------------------------------
// Rotate src points (reads packed kvcat, kvp part at offset 384).
// Writes TRANSPOSED: kpT[h*12+pq*3+ax][j], vAllT[h*40+16+pv*3+ax][j], sqkT[h][j]
// ---------------------------------------------------------------------------
__global__ __launch_bounds__(192) void rot_src_kernel(
    const float* __restrict__ kvcat, const float* __restrict__ Rs,
    const float* __restrict__ ts, float* __restrict__ kpT,
    float* __restrict__ vAllT, float* __restrict__ sqkT)
{
    const int j = blockIdx.x, t = threadIdx.x;
    __shared__ float part[48];
    if (t < 144) {
        float x = kvcat[(size_t)j * KVW + 384 + t];
        float y = kvcat[(size_t)j * KVW + 384 + 144 + t];
        float z = kvcat[(size_t)j * KVW + 384 + 288 + t];
        const float* R = Rs + j * 9;
        float rx = R[0] * x + R[1] * y + R[2] * z + ts[j * 3 + 0];
        float ry = R[3] * x + R[4] * y + R[5] * z + ts[j * 3 + 1];
        float rz = R[6] * x + R[7] * y + R[8] * z + ts[j * 3 + 2];
        int h = t / 12, pp = t % 12;
        if (pp < 4) {
            size_t o = ((size_t)h * 12 + pp * 3) * LS + j;
            kpT[o] = rx; kpT[o + LS] = ry; kpT[o + 2 * LS] = rz;
            part[h * 4 + pp] = rx * rx + ry * ry + rz * rz;
        } else {
            size_t o = ((size_t)h * 40 + 16 + (pp - 4) * 3) * LS + j;
            vAllT[o] = rx; vAllT[o + LS] = ry; vAllT[o + 2 * LS] = rz;
        }
    }
    __syncthreads();
    if (t < NH) sqkT[(size_t)t * LS + j] = part[t * 4] + part[t * 4 + 1] + part[t * 4 + 2] + part[t * 4 + 3];
}

// ---------------------------------------------------------------------------
// Transpose kvcat[j][h*32+c] -> kT[h*16+c][j] (c<16) / vAllT[h*40+c-16][j]
// ---------------------------------------------------------------------------
__global__ __launch_bounds__(256) void transpose_kv_kernel(
    const float* __restrict__ kvcat, float* __restrict__ kT,
    float* __restrict__ vAllT)
{
    const int h = blockIdx.y, j0 = blockIdx.x * 64, t = threadIdx.x;
    __shared__ float tile[64][33];
#pragma unroll
    for (int r = 0; r < 2; ++r) {
        int f = t + r * 256;
        int jl = f >> 3, c4 = (f & 7) * 4;
        float4 v = *(const float4*)(kvcat + (size_t)(j0 + jl) * KVW + h * 32 + c4);
        tile[jl][c4 + 0] = v.x;
        tile[jl][c4 + 1] = v.y;
        tile[jl][c4 + 2] = v.z;
        tile[jl][c4 + 3] = v.w;
    }
    __syncthreads();
    const int jl = t & 63, cr = t >> 6;
#pragma unroll
    for (int cg = 0; cg < 8; ++cg) {
        int c = cg * 4 + cr;
        float v = tile[jl][c];
        if (c < 16) kT[((size_t)h * 16 + c) * LS + j0 + jl] = v;
        else        vAllT[((size_t)h * 40 + (c - 16)) * LS + j0 + jl] = v;
    }
}

// ---------------------------------------------------------------------------
// Scores + softmax. LDS-staged q-side (q from qcat, qp from ROTATED qp_rot)
// + coalesced transposed k-side. asd/apts are pure-write -> nontemporal
// stores; a_out stays cached (av_mfma re-reads it from L2).
// ---------------------------------------------------------------------------
__global__ __launch_bounds__(256) void score_softmax_kernel(
    const float* __restrict__ qb, const float* __restrict__ kT,
    const float* __restrict__ qpb, const float* __restrict__ kpT,
    const float* __restrict__ sqq_g, const float* __restrict__ sqkT,
    const float* __restrict__ dmask, const float* __restrict__ smask,
    const float* __restrict__ head_w,
    float* __restrict__ a_out, float* __restrict__ asd_out,
    float* __restrict__ apts_out)
{
    const int h = blockIdx.y;
    const int i0 = blockIdx.x * 4;
    const int t = threadIdx.x;

    __shared__ float qs[4][32];   // [i][0:16]=q, [16:28]=rotated qp, pad
    __shared__ float sqq_s[4];
    __shared__ float dm_s[4];
    __shared__ float red[4][4];

    if (t < 128) {
        int i = t >> 5, c = t & 31;
        float v = 0.f;
        if (c < 16)      v = qb[(size_t)(i0 + i) * QCW + h * CH + c];
        else if (c < 28) v = qpb[(size_t)(i0 + i) * 144 + h * 12 + (c - 16)];
        qs[i][c] = v;
    } else if (t < 132) {
        int i = t - 128;
        sqq_s[i] = sqq_g[(size_t)(i0 + i) * NH + h];
        dm_s[i] = dmask[i0 + i];
    }
    const float hwv = log1pf(__expf(head_w[h])) * (1.0f / 6.0f);
    const float s1 = 0.17677669529663687f;  // sqrt(1/32)
    const size_t rowbase = ((size_t)h * LD + i0) * LS;
    __syncthreads();

    float4 sregv[4][2];
    float mx[4] = {-3.0e38f, -3.0e38f, -3.0e38f, -3.0e38f};

#pragma unroll
    for (int jc = 0; jc < 2; ++jc) {
        const int j = (jc * 256 + t) * 4;
        float4 sm4 = *(const float4*)(smask + j);
        float4 sqk4 = *(const float4*)(sqkT + (size_t)h * LS + j);

        // Burst-load all 16 k rows (independent 16B loads -> deep MLP)
        float4 kk[16];
#pragma unroll
        for (int c = 0; c < 16; ++c)
            kk[c] = *(const float4*)(kT + ((size_t)h * 16 + c) * LS + j);

        float4 qk4[4];
#pragma unroll
        for (int i = 0; i < 4; ++i) {
            const float4* q4 = (const float4*)&qs[i][0];
            float4 q0 = q4[0], q1 = q4[1], q2 = q4[2], q3 = q4[3];
            float4 a;
            a.x = q0.x * kk[0].x + q0.y * kk[1].x + q0.z * kk[2].x + q0.w * kk[3].x
                + q1.x * kk[4].x + q1.y * kk[5].x + q1.z * kk[6].x + q1.w * kk[7].x
                + q2.x * kk[8].x + q2.y * kk[9].x + q2.z * kk[10].x + q2.w * kk[11].x
                + q3.x * kk[12].x + q3.y * kk[13].x + q3.z * kk[14].x + q3.w * kk[15].x;
            a.y = q0.x * kk[0].y + q0.y * kk[1].y + q0.z * kk[2].y + q0.w * kk[3].y
                + q1.x * kk[4].y + q1.y * kk[5].y + q1.z * kk[6].y + q1.w * kk[7].y
                + q2.x * kk[8].y + q2.y * kk[9].y + q2.z * kk[10].y + q2.w * kk[11].y
                + q3.x * kk[12].y + q3.y * kk[13].y + q3.z * kk[14].y + q3.w * kk[15].y;
            a.z = q0.x * kk[0].z + q0.y * kk[1].z + q0.z * kk[2].z + q0.w * kk[3].z
                + q1.x * kk[4].z + q1.y * kk[5].z + q1.z * kk[6].z + q1.w * kk[7].z
                + q2.x * kk[8].z + q2.y * kk[9].z + q2.z * kk[10].z + q2.w * kk[11].z
                + q3.x * kk[12].z + q3.y * kk[13].z + q3.z * kk[14].z + q3.w * kk[15].z;
            a.w = q0.x * kk[0].w + q0.y * kk[1].w + q0.z * kk[2].w + q0.w * kk[3].w
                + q1.x * kk[4].w + q1.y * kk[5].w + q1.z * kk[6].w + q1.w * kk[7].w
                + q2.x * kk[8].w + q2.y * kk[9].w + q2.z * kk[10].w + q2.w * kk[11].w
                + q3.x * kk[12].w + q3.y * kk[13].w + q3.z * kk[14].w + q3.w * kk[15].w;
            qk4[i] = a;
        }

        // Burst-load all 12 kp rows
        float4 pp[12];
#pragma unroll
        for (int d = 0; d < 12; ++d)
            pp[d] = *(const float4*)(kpT + ((size_t)h * 12 + d) * LS + j);

        float4 dp4[4];
#pragma unroll
        for (int i = 0; i < 4; ++i) {
            const float4* r4 = (const float4*)&qs[i][16];
            float4 r0 = r4[0], r1 = r4[1], r2 = r4[2];
            float4 d;
            d.x = r0.x * pp[0].x + r0.y * pp[1].x + r0.z * pp[2].x + r0.w * pp[3].x
                + r1.x * pp[4].x + r1.y * pp[5].x + r1.z * pp[6].x + r1.w * pp[7].x
                + r2.x * pp[8].x + r2.y * pp[9].x + r2.z * pp[10].x + r2.w * pp[11].x;
            d.y = r0.x * pp[0].y + r0.y * pp[1].y + r0.z * pp[2].y + r0.w * pp[3].y
                + r1.x * pp[4].y + r1.y * pp[5].y + r1.z * pp[6].y + r1.w * pp[7].y
                + r2.x * pp[8].y + r2.y * pp[9].y + r2.z * pp[10].y + r2.w * pp[11].y;
            d.z = r0.x * pp[0].z + r0.y * pp[1].z + r0.z * pp[2].z + r0.w * pp[3].z
                + r1.x * pp[4].z + r1.y * pp[5].z + r1.z * pp[6].z + r1.w * pp[7].z
                + r2.x * pp[8].z + r2.y * pp[9].z + r2.z * pp[10].z + r2.w * pp[11].z;
            d.w = r0.x * pp[0].w + r0.y * pp[1].w + r0.z * pp[2].w + r0.w * pp[3].w
                + r1.x * pp[4].w + r1.y * pp[5].w + r1.z * pp[6].w + r1.w * pp[7].w
                + r2.x * pp[8].w + r2.y * pp[9].w + r2.z * pp[10].w + r2.w * pp[11].w;
            dp4[i] = d;
        }

#pragma unroll
        for (int i = 0; i < 4; ++i) {
            float sqq = sqq_s[i];
            float dm = dm_s[i];
            float4 qk, pt, g, logit;
            qk.x = qk4[i].x * s1; qk.y = qk4[i].y * s1;
            qk.z = qk4[i].z * s1; qk.w = qk4[i].w * s1;
            pt.x = -0.5f * hwv * (sqq + sqk4.x - 2.f * dp4[i].x);
            pt.y = -0.5f * hwv * (sqq + sqk4.y - 2.f * dp4[i].y);
            pt.z = -0.5f * hwv * (sqq + sqk4.z - 2.f * dp4[i].z);
            pt.w = -0.5f * hwv * (sqq + sqk4.w - 2.f * dp4[i].w);
            g.x = dm * sm4.x; g.y = dm * sm4.y; g.z = dm * sm4.z; g.w = dm * sm4.w;
            size_t idx = rowbase + (size_t)i * LS + j;
            f32x4 asd = {qk.x * g.x, qk.y * g.y, qk.z * g.z, qk.w * g.w};
            f32x4 apts = {pt.x * g.x, pt.y * g.y, pt.z * g.z, pt.w * g.w};
            __builtin_nontemporal_store(asd, (f32x4*)(asd_out + idx));
            __builtin_nontemporal_store(apts, (f32x4*)(apts_out + idx));
            logit.x = qk.x + pt.x + 1.0e9f * (g.x - 1.0f);
            logit.y = qk.y + pt.y + 1.0e9f * (g.y - 1.0f);
            logit.z = qk.z + pt.z + 1.0e9f * (g.z - 1.0f);
            logit.w = qk.w + pt.w + 1.0e9f * (g.w - 1.0f);
            sregv[i][jc] = logit;
            mx[i] = fmaxf(mx[i], fmaxf(fmaxf(logit.x, logit.y), fmaxf(logit.z, logit.w)));
        }
    }

    const int lane = t & 63, wid = t >> 6;
#pragma unroll
    for (int i = 0; i < 4; ++i) {
        float v = mx[i];
        for (int off = 32; off > 0; off >>= 1) v = fmaxf(v, __shfl_xor(v, off));
        if (lane == 0) red[wid][i] = v;
    }
    __syncthreads();
    float M[4], sum[4] = {0.f, 0.f, 0.f, 0.f};
#pragma unroll
    for (int i = 0; i < 4; ++i)
        M[i] = fmaxf(fmaxf(red[0][i], red[1][i]), fmaxf(red[2][i], red[3][i]));
    __syncthreads();

#pragma unroll
    for (int jc = 0; jc < 2; ++jc) {
#pragma unroll
        for (int i = 0; i < 4; ++i) {
            float4 e;
            e.x = __expf(sregv[i][jc].x - M[i]);
            e.y = __expf(sregv[i][jc].y - M[i]);
            e.z = __expf(sregv[i][jc].z - M[i]);
            e.w = __expf(sregv[i][jc].w - M[i]);
            sregv[i][jc] = e;
            sum[i] += e.x + e.y + e.z + e.w;
        }
    }
#pragma unroll
    for (int i = 0; i < 4; ++i) {
        float v = sum[i];
        for (int off = 32; off > 0; off >>= 1) v += __shfl_xor(v, off);
        if (lane == 0) red[wid][i] = v;
    }
    __syncthreads();
    float inv[4];
#pragma unroll
    for (int i = 0; i < 4; ++i)
        inv[i] = 1.0f / (red[0][i] + red[1][i] + red[2][i] + red[3][i]);

#pragma unroll
    for (int jc = 0; jc < 2; ++jc) {
        const int j = (jc * 256 + t) * 4;
#pragma unroll
        for (int i = 0; i < 4; ++i) {
            float4 e = sregv[i][jc];
            float4 o = make_float4(e.x * inv[i], e.y * inv[i], e.z * inv[i], e.w * inv[i]);
            *(float4*)(a_out + rowbase + (size_t)i * LS + j) = o;
        }
    }
}

// ---------------------------------------------------------------------------
// AV via MFMA, split-bf16. 512 threads = 8 waves; each wave owns a disjoint
// CONTIGUOUS 256-wide K-chunk (8 x 256 = LS = 2048). Partials reduced across
// waves in LDS (padded inner dim 13 -> conflict-free), wave 0 stores.
// No atomics, no memset prerequisite.
// ---------------------------------------------------------------------------
__global__ __launch_bounds__(512) void av_mfma_kernel(
    const float* __restrict__ a, const float* __restrict__ vAllT,
    float* __restrict__ o_buf, float* __restrict__ opt_buf)
{
    const int m0 = blockIdx.x * 16;
    const int h  = blockIdx.y;
    const int t = threadIdx.x;
    const int lane = t & 63;
    const int wid  = t >> 6;            // 0..7 -> K-chunk of 256
    const int row16 = lane & 15, kq = lane >> 4;

    const size_t kbase = (size_t)wid * 256 + kq * 8;
    const float* ap  = a     + ((size_t)h * LD + m0 + row16) * LS + kbase;
    const float* v0p = vAllT + ((size_t)h * 40 +  0 + row16) * LS + kbase;
    const float* v1p = vAllT + ((size_t)h * 40 + 16 + row16) * LS + kbase;
    const float* v2p = vAllT + ((size_t)h * 40 + 24 + row16) * LS + kbase;

    f32x4 acc0 = {0.f, 0.f, 0.f, 0.f};
    f32x4 acc1 = {0.f, 0.f, 0.f, 0.f};
    f32x4 acc2 = {0.f, 0.f, 0.f, 0.f};

#pragma unroll 2
    for (int kk = 0; kk < 256; kk += 32) {
        bf16x8 ah, al, bh, bl;
        split_frag(ap + kk, ah, al);

        split_frag(v0p + kk, bh, bl);
        acc0 = __builtin_amdgcn_mfma_f32_16x16x32_bf16(ah, bh, acc0, 0, 0, 0);
        acc0 = __builtin_amdgcn_mfma_f32_16x16x32_bf16(ah, bl, acc0, 0, 0, 0);
        acc0 = __builtin_amdgcn_mfma_f32_16x16x32_bf16(al, bh, acc0, 0, 0, 0);

        split_frag(v1p + kk, bh, bl);
        acc1 = __builtin_amdgcn_mfma_f32_16x16x32_bf16(ah, bh, acc1, 0, 0, 0);
        acc1 = __builtin_amdgcn_mfma_f32_16x16x32_bf16(ah, bl, acc1, 0, 0, 0);
        acc1 = __builtin_amdgcn_mfma_f32_16x16x32_bf16(al, bh, acc1, 0, 0, 0);

        split_frag(v2p + kk, bh, bl);
        acc2 = __builtin_amdgcn_mfma_f32_16x16x32_bf16(ah, bh, acc2, 0, 0, 0);
        acc2 = __builtin_amdgcn_mfma_f32_16x16x32_bf16(ah, bl, acc2, 0, 0, 0);
        acc2 = __builtin_amdgcn_mfma_f32_16x16x32_bf16(al, bh, acc2, 0, 0, 0);
    }

    // Cross-wave reduction in LDS. Inner dim padded to 13 (odd stride -> 2
    // lanes/bank for the lane-indexed access = conflict-free per m136).
    __shared__ float red[8][64][13];
#pragma unroll
    for (int r = 0; r < 4; ++r) {
        red[wid][lane][r]     = acc0[r];
        red[wid][lane][4 + r] = acc1[r];
        red[wid][lane][8 + r] = acc2[r];
    }
    __syncthreads();

    if (wid == 0) {
        float s[12];
#pragma unroll
        for (int r = 0; r < 12; ++r) {
            float v = red[0][lane][r];
#pragma unroll
            for (int w = 1; w < 8; ++w) v += red[w][lane][r];
            s[r] = v;
        }
        const int ib = m0 + kq * 4;
#pragma unroll
        for (int r = 0; r < 4; ++r) {
            const int i = ib + r;
            o_buf[(size_t)i * 192 + h * 16 + row16] = s[r];
            opt_buf[(size_t)i * 288 + h * 24 + row16] = s[4 + r];
            if (row16 >= 8)
                opt_buf[(size_t)i * 288 + h * 24 + 8 + row16] = s[8 + r];
        }
    }
}

// ---------------------------------------------------------------------------
// Finalize: cat = [o(192) | x(96) | y(96) | z(96) | norm(96)]
// ---------------------------------------------------------------------------
__global__ __launch_bounds__(192) void finalize_kernel(
    const float* __restrict__ o_buf, const float* __restrict__ opt_buf,
    const float* __restrict__ Rd, const float* __restrict__ td,
    float* __restrict__ cat)
{
    const int i = blockIdx.x, t = threadIdx.x;
    cat[i * 576 + t] = o_buf[i * 192 + t];
    if (t < 96) {
        const float* op = opt_buf + i * 288 + t * 3;
        float x = op[0] - td[i * 3 + 0];
        float y = op[1] - td[i * 3 + 1];
        float z = op[2] - td[i * 3 + 2];
        const float* R = Rd + i * 9;
        float rx = R[0] * x + R[3] * y + R[6] * z;
        float ry = R[1] * x + R[4] * y + R[7] * z;
        float rz = R[2] * x + R[5] * y + R[8] * z;
        float* cc = cat + i * 576 + 192;
        cc[t] = rx;
        cc[96 + t] = ry;
        cc[192 + t] = rz;
        cc[288 + t] = sqrtf(rx * rx + ry * ry + rz * rz + 1e-8f);
    }
}

// ---------------------------------------------------------------------------
extern "C" void kernel_launch(void* const* d_in, const int* in_sizes, int n_in,
                              void* d_out, int out_size, void* d_ws, size_t ws_size,
                              hipStream_t stream)
{
    (void)in_sizes; (void)n_in; (void)out_size; (void)ws_size;
    const float* s_dst    = (const float*)d_in[0];
    const float* s_src    = (const float*)d_in[1];
    const float* R_dst    = (const float*)d_in[2];
    const float* t_dst    = (const float*)d_in[3];
    const float* R_src    = (const float*)d_in[4];
    const float* t_src    = (const float*)d_in[5];
    const float* dst_mask = (const float*)d_in[6];
    const float* src_mask = (const float*)d_in[7];
    const float* W_q      = (const float*)d_in[8];
    const float* W_kv     = (const float*)d_in[9];
    const float* W_qp     = (const float*)d_in[10];
    const float* W_kvp    = (const float*)d_in[11];
    const float* W_out    = (const float*)d_in[12];
    const float* b_out    = (const float*)d_in[13];
    const float* head_w   = (const float*)d_in[14];

    float* ws = (float*)d_ws;
    float* qcat    = ws;                    // 512*336    = 172032
    float* kvcat   = qcat    + 172032;      // 2048*816   = 1671168
    float* qp_rot  = kvcat   + 1671168;     // 512*144    = 73728
    float* sq_q    = qp_rot  + 73728;       // 512*12     = 6144
    float* o_buf   = sq_q    + 6144;        // 512*192    = 98304
    float* opt_buf = o_buf   + 98304;       // 512*288    = 147456 (contiguous after o_buf)
    float* cat_buf = opt_buf + 147456;      // 512*576    = 294912
    float* kT      = cat_buf + 294912;      // 12*16*2048 = 393216
    float* vAllT   = kT      + 393216;      // 12*40*2048 = 983040
    float* kpT     = vAllT   + 983040;      // 12*12*2048 = 294912
    float* sqkT    = kpT     + 294912;      // 12*2048    = 24576
    float* Wt_qc   = sqkT    + 24576;       // 336*384    = 129024
    float* Wt_kvc  = Wt_qc   + 129024;      // 816*384    = 313344
    float* Wt_out  = Wt_kvc  + 313344;      // 384*576    = 221184

    float* out_s    = (float*)d_out;              // 512*384
    float* out_a    = out_s    + 196608;          // 12*512*2048
    float* out_asd  = out_a    + 12582912;
    float* out_apts = out_asd  + 12582912;

    dim3 b256(256);
    // Weight transposes into packed Bt layouts
    transpose_w_kernel<<<dim3(12,  6), b256, 0, stream>>>(W_q,   Wt_qc,              384, 192);
    transpose_w_kernel<<<dim3(12,  5), b256, 0, stream>>>(W_qp,  Wt_qc  + 192 * 384, 384, 144);
    transpose_w_kernel<<<dim3(12, 12), b256, 0, stream>>>(W_kv,  Wt_kvc,             384, 384);
    transpose_w_kernel<<<dim3(12, 14), b256, 0, stream>>>(W_kvp, Wt_kvc + 384 * 384, 384, 432);
    transpose_w_kernel<<<dim3(18, 12), b256, 0, stream>>>(W_out, Wt_out,             576, 384);
    // Projections via MFMA split-bf16
    mfma_gemm_bt_kernel<<<dim3(16, 11), dim3(64), 0, stream>>>(s_dst, Wt_qc,  nullptr, qcat,  LD, QCW, CS);
    mfma_gemm_bt_kernel<<<dim3(64, 26), dim3(64), 0, stream>>>(s_src, Wt_kvc, nullptr, kvcat, LS, KVW, CS);
    // Rotations + squared norms (src writes transposed) + kv transpose
    rot_dst_kernel<<<LD, 64, 0, stream>>>(qcat, R_dst, t_dst, qp_rot, sq_q);
    rot_src_kernel<<<LS, 192, 0, stream>>>(kvcat, R_src, t_src, kpT, vAllT, sqkT);
    transpose_kv_kernel<<<dim3(32, 12), b256, 0, stream>>>(kvcat, kT, vAllT);
    // Scores + softmax (+ a_sd, a_pts, a outputs)
    score_softmax_kernel<<<dim3(LD / 4, NH), b256, 0, stream>>>(
        qcat, kT, qp_rot, kpT, sq_q, sqkT, dst_mask, src_mask, head_w,
        out_a, out_asd, out_apts);
    // MFMA AV: 8-wave blocks, K split across waves (8 x 256 = 2048), LDS reduce
    av_mfma_kernel<<<dim3(LD / 16, NH), dim3(512), 0, stream>>>(out_a, vAllT, o_buf, opt_buf);
    // Inverse rotation, norms, concat
    finalize_kernel<<<LD, 192, 0, stream>>>(o_buf, opt_buf, R_dst, t_dst, cat_buf);
    // Output projection via MFMA split-bf16 (+bias)
    mfma_gemm_bt_kernel<<<dim3(16, 12), dim3(64), 0, stream>>>(cat_buf, Wt_out, b_out, out_s, LD, CS, 576);
}

// Round 3
// 305.779 us; speedup vs baseline: 1.0850x; 1.0850x over previous
//
#include <hip/hip_runtime.h>
#include <hip/hip_bf16.h>

// Problem constants
#define LD 512
#define LS 2048
#define CS 384
#define CH 16
#define NH 12
#define PQ 4
#define PV 8
#define QCW 336   // packed [q(192) | qp(144)] row width
#define KVW 816   // packed [kv(384) | kvp(432)] row width

typedef __bf16 bf16x8 __attribute__((ext_vector_type(8)));
typedef float  f32x4  __attribute__((ext_vector_type(4)));

// ---------------------------------------------------------------------------
// Split an 8-float run into bf16 hi/lo fragments (hi + lo ~= fp32 value).
// ---------------------------------------------------------------------------
__device__ inline void split_frag(const float* __restrict__ p, bf16x8& hi, bf16x8& lo)
{
    float4 x = *(const float4*)p;
    float4 y = *(const float4*)(p + 4);
    float f[8] = {x.x, x.y, x.z, x.w, y.x, y.y, y.z, y.w};
#pragma unroll
    for (int e = 0; e < 8; ++e) {
        __bf16 h = (__bf16)f[e];
        hi[e] = h;
        lo[e] = (__bf16)(f[e] - (float)h);
    }
}

// ---------------------------------------------------------------------------
// ALL weight transposes in ONE launch. Per-block segment lookup, then the
// standard 32x32 LDS-tile transpose. 660 blocks total.
//   seg0: W_q   384x192 -> Wt_qc          (grid 12x6  = 72)
//   seg1: W_qp  384x144 -> Wt_qc+192*384  (grid 12x5  = 60)
//   seg2: W_kv  384x384 -> Wt_kvc         (grid 12x12 = 144)
//   seg3: W_kvp 384x432 -> Wt_kvc+384*384 (grid 12x14 = 168)
//   seg4: W_out 576x384 -> Wt_out         (grid 18x12 = 216)
// ---------------------------------------------------------------------------
__global__ __launch_bounds__(256) void transpose_w_all_kernel(
    const float* __restrict__ W_q, const float* __restrict__ W_kv,
    const float* __restrict__ W_qp, const float* __restrict__ W_kvp,
    const float* __restrict__ W_out,
    float* __restrict__ Wt_qc, float* __restrict__ Wt_kvc,
    float* __restrict__ Wt_out)
{
    int b = blockIdx.x;
    const float* src; float* dst; int R, Cc, gx;
    if (b < 72)       {         src = W_q;   dst = Wt_qc;             R = 384; Cc = 192; gx = 12; }
    else if (b < 132) { b -= 72;  src = W_qp;  dst = Wt_qc + 192*384; R = 384; Cc = 144; gx = 12; }
    else if (b < 276) { b -= 132; src = W_kv;  dst = Wt_kvc;          R = 384; Cc = 384; gx = 12; }
    else if (b < 444) { b -= 276; src = W_kvp; dst = Wt_kvc + 384*384;R = 384; Cc = 432; gx = 12; }
    else              { b -= 444; src = W_out; dst = Wt_out;          R = 576; Cc = 384; gx = 18; }
    const int r0 = (b % gx) * 32, c0 = (b / gx) * 32;

    __shared__ float tile[32][33];
    const int tx = threadIdx.x & 31, ty = threadIdx.x >> 5;  // ty 0..7
#pragma unroll
    for (int rr = 0; rr < 32; rr += 8) {
        int r = r0 + ty + rr, c = c0 + tx;
        tile[ty + rr][tx] = (r < R && c < Cc) ? src[(size_t)r * Cc + c] : 0.f;
    }
    __syncthreads();
#pragma unroll
    for (int rr = 0; rr < 32; rr += 8) {
        int c = c0 + ty + rr, r = r0 + tx;
        if (c < Cc && r < R) dst[(size_t)c * R + r] = tile[tx][ty + rr];
    }
}

// ---------------------------------------------------------------------------
// MFMA GEMM, split-bf16 3-pass: C[M][N] = A[M][K] @ Bt[N][K]^T (+bias).
// ---------------------------------------------------------------------------
__global__ __launch_bounds__(64) void mfma_gemm_bt_kernel(
    const float* __restrict__ A, const float* __restrict__ Bt,
    const float* __restrict__ bias, float* __restrict__ C,
    int M, int N, int K)
{
    const int m0 = blockIdx.x * 32;
    const int n0 = blockIdx.y * 32;
    const int lane = threadIdx.x;
    const int row16 = lane & 15, kq = lane >> 4;

    const float* ap0 = A + (size_t)(m0 + row16) * K + kq * 8;
    const float* ap1 = ap0 + (size_t)16 * K;
    const float* bp0 = Bt + (size_t)(n0 + row16) * K + kq * 8;
    const float* bp1 = bp0 + (size_t)16 * K;
    const bool n1ok = (n0 + 16) < N;

    f32x4 acc00 = {0.f, 0.f, 0.f, 0.f};
    f32x4 acc10 = {0.f, 0.f, 0.f, 0.f};
    f32x4 acc01 = {0.f, 0.f, 0.f, 0.f};
    f32x4 acc11 = {0.f, 0.f, 0.f, 0.f};

    for (int k = 0; k < K; k += 32) {
        bf16x8 a0h, a0l, a1h, a1l, b0h, b0l, b1h, b1l;
        split_frag(ap0 + k, a0h, a0l);
        split_frag(ap1 + k, a1h, a1l);
        split_frag(bp0 + k, b0h, b0l);
        acc00 = __builtin_amdgcn_mfma_f32_16x16x32_bf16(a0h, b0h, acc00, 0, 0, 0);
        acc00 = __builtin_amdgcn_mfma_f32_16x16x32_bf16(a0h, b0l, acc00, 0, 0, 0);
        acc00 = __builtin_amdgcn_mfma_f32_16x16x32_bf16(a0l, b0h, acc00, 0, 0, 0);
        acc10 = __builtin_amdgcn_mfma_f32_16x16x32_bf16(a1h, b0h, acc10, 0, 0, 0);
        acc10 = __builtin_amdgcn_mfma_f32_16x16x32_bf16(a1h, b0l, acc10, 0, 0, 0);
        acc10 = __builtin_amdgcn_mfma_f32_16x16x32_bf16(a1l, b0h, acc10, 0, 0, 0);
        if (n1ok) {
            split_frag(bp1 + k, b1h, b1l);
            acc01 = __builtin_amdgcn_mfma_f32_16x16x32_bf16(a0h, b1h, acc01, 0, 0, 0);
            acc01 = __builtin_amdgcn_mfma_f32_16x16x32_bf16(a0h, b1l, acc01, 0, 0, 0);
            acc01 = __builtin_amdgcn_mfma_f32_16x16x32_bf16(a0l, b1h, acc01, 0, 0, 0);
            acc11 = __builtin_amdgcn_mfma_f32_16x16x32_bf16(a1h, b1h, acc11, 0, 0, 0);
            acc11 = __builtin_amdgcn_mfma_f32_16x16x32_bf16(a1h, b1l, acc11, 0, 0, 0);
            acc11 = __builtin_amdgcn_mfma_f32_16x16x32_bf16(a1l, b1h, acc11, 0, 0, 0);
        }
    }

    const float bv0 = bias ? bias[n0 + row16] : 0.f;
    const float bv1 = (bias && n1ok) ? bias[n0 + 16 + row16] : 0.f;
#pragma unroll
    for (int r = 0; r < 4; ++r) {
        const int mA = m0 + kq * 4 + r;
        const int mB = mA + 16;
        C[(size_t)mA * N + n0 + row16] = acc00[r] + bv0;
        C[(size_t)mB * N + n0 + row16] = acc10[r] + bv0;
        if (n1ok) {
            C[(size_t)mA * N + n0 + 16 + row16] = acc01[r] + bv1;
            C[(size_t)mB * N + n0 + 16 + row16] = acc11[r] + bv1;
        }
    }
}

// ---------------------------------------------------------------------------
// FUSED prep: replaces rot_src + transpose_kv + rot_dst (3 launches -> 1).
// grid (32, 13), 256 threads.
//   blockIdx.y < 12 : head h, j-tile of 64.
//     - kv transpose via 64x33 LDS tile (same as old transpose_kv slice)
//     - rotate the 12 src points of head h for 64 j, stage rows in LDS
//       [36][64], then write COALESCED 64-wide runs to kpT / vAllT
//       (old rot_src wrote 4B-scattered stride-LS columns)
//     - sqkT row for head h
//   blockIdx.y == 12 : dst-side rotation (16 i per block), qp_rot + sqq.
// Arithmetic identical to the three old kernels.
// ---------------------------------------------------------------------------
__global__ __launch_bounds__(256) void prep_kernel(
    const float* __restrict__ qcat, const float* __restrict__ kvcat,
    const float* __restrict__ Rd, const float* __restrict__ td,
    const float* __restrict__ Rs, const float* __restrict__ ts,
    float* __restrict__ qp_rot, float* __restrict__ sqq,
    float* __restrict__ kT, float* __restrict__ vAllT,
    float* __restrict__ kpT, float* __restrict__ sqkT)
{
    const int t = threadIdx.x;
    if (blockIdx.y < NH) {
        const int h = blockIdx.y, j0 = blockIdx.x * 64;
        __shared__ float tile[64][33];
        __shared__ float ot[36][64];
        __shared__ float nrm[64][4];
        __shared__ float rt[64][12];

        // Stage R_src (9) + t_src (3) per j: 768 = 3*256 values.
#pragma unroll
        for (int s = 0; s < 3; ++s) {
            int ld = t + s * 256;
            int jl = ld / 12, q = ld % 12;
            rt[jl][q] = (q < 9) ? Rs[(size_t)(j0 + jl) * 9 + q]
                                : ts[(size_t)(j0 + jl) * 3 + (q - 9)];
        }
        // kv tile load (64 j x 32 ch of head h)
#pragma unroll
        for (int r = 0; r < 2; ++r) {
            int f = t + r * 256;
            int jl = f >> 3, c4 = (f & 7) * 4;
            float4 v = *(const float4*)(kvcat + (size_t)(j0 + jl) * KVW + h * 32 + c4);
            tile[jl][c4 + 0] = v.x;
            tile[jl][c4 + 1] = v.y;
            tile[jl][c4 + 2] = v.z;
            tile[jl][c4 + 3] = v.w;
        }
        __syncthreads();

        // kv transpose write: c<16 -> kT rows, c in [16,32) -> vAllT rows 0..15
        {
            const int jl = t & 63, cr = t >> 6;
#pragma unroll
            for (int cg = 0; cg < 8; ++cg) {
                int c = cg * 4 + cr;
                float v = tile[jl][c];
                if (c < 16) kT[((size_t)h * 16 + c) * LS + j0 + jl] = v;
                else        vAllT[((size_t)h * 40 + (c - 16)) * LS + j0 + jl] = v;
            }
        }

        // Rotate the 12 points of head h for each of 64 j (768 = 3*256 pairs).
#pragma unroll
        for (int s = 0; s < 3; ++s) {
            int u = t + s * 256;
            int jl = u / 12, p = u % 12;
            const float* src = kvcat + (size_t)(j0 + jl) * KVW + 384 + h * 12 + p;
            float x = src[0], y = src[144], z = src[288];
            const float* R = &rt[jl][0];
            float rx = R[0] * x + R[1] * y + R[2] * z + R[9];
            float ry = R[3] * x + R[4] * y + R[5] * z + R[10];
            float rz = R[6] * x + R[7] * y + R[8] * z + R[11];
            if (p < 4) {
                ot[p * 3 + 0][jl] = rx;
                ot[p * 3 + 1][jl] = ry;
                ot[p * 3 + 2][jl] = rz;
                nrm[jl][p] = rx * rx + ry * ry + rz * rz;
            } else {
                int r0 = 12 + (p - 4) * 3;
                ot[r0 + 0][jl] = rx;
                ot[r0 + 1][jl] = ry;
                ot[r0 + 2][jl] = rz;
            }
        }
        __syncthreads();

        // Coalesced row writes: rows 0..11 -> kpT[h*12+row], 12..35 -> vAllT
        // rows h*40+16..h*40+39. 2304 = 9*256 values.
#pragma unroll
        for (int w = 0; w < 9; ++w) {
            int idx = t + w * 256;
            int row = idx >> 6, jl = idx & 63;
            float v = ot[row][jl];
            if (row < 12) kpT[((size_t)h * 12 + row) * LS + j0 + jl] = v;
            else          vAllT[((size_t)h * 40 + 16 + (row - 12)) * LS + j0 + jl] = v;
        }
        if (t < 64)
            sqkT[(size_t)h * LS + j0 + t] = nrm[t][0] + nrm[t][1] + nrm[t][2] + nrm[t][3];
    } else {
        // dst-side rotation: 16 i per block (32 blocks x 16 = 512).
        const int i0 = blockIdx.x * 16;
        __shared__ float part[16][48];
        __shared__ float rtd[16][12];
        if (t < 192) {
            int il = t / 12, q = t % 12;
            rtd[il][q] = (q < 9) ? Rd[(size_t)(i0 + il) * 9 + q]
                                 : td[(size_t)(i0 + il) * 3 + (q - 9)];
        }
        __syncthreads();
#pragma unroll
        for (int s = 0; s < 3; ++s) {
            int u = t + s * 256;      // 768 = 16*48
            int il = u / 48, pt = u % 48;
            int i = i0 + il;
            float x = qcat[(size_t)i * QCW + 192 + pt];
            float y = qcat[(size_t)i * QCW + 240 + pt];
            float z = qcat[(size_t)i * QCW + 288 + pt];
            const float* R = &rtd[il][0];
            float rx = R[0] * x + R[1] * y + R[2] * z + R[9];
            float ry = R[3] * x + R[4] * y + R[5] * z + R[10];
            float rz = R[6] * x + R[7] * y + R[8] * z + R[11];
            qp_rot[(size_t)i * 144 + pt * 3 + 0] = rx;
            qp_rot[(size_t)i * 144 + pt * 3 + 1] = ry;
            qp_rot[(size_t)i * 144 + pt * 3 + 2] = rz;
            part[il][pt] = rx * rx + ry * ry + rz * rz;
        }
        __syncthreads();
        if (t < 192) {
            int il = t / 12, hh = t % 12;
            sqq[(size_t)(i0 + il) * NH + hh] =
                part[il][hh * 4] + part[il][hh * 4 + 1] +
                part[il][hh * 4 + 2] + part[il][hh * 4 + 3];
        }
    }
}

// ---------------------------------------------------------------------------
// Scores + softmax. LDS-staged q-side (q from qcat, qp from ROTATED qp_rot)
// + coalesced transposed k-side. asd/apts are pure-write -> nontemporal
// stores; a_out stays cached (av_mfma re-reads it from L2/L3).
// ---------------------------------------------------------------------------
__global__ __launch_bounds__(256) void score_softmax_kernel(
    const float* __restrict__ qb, const float* __restrict__ kT,
    const float* __restrict__ qpb, const float* __restrict__ kpT,
    const float* __restrict__ sqq_g, const float* __restrict__ sqkT,
    const float* __restrict__ dmask, const float* __restrict__ smask,
    const float* __restrict__ head_w,
    float* __restrict__ a_out, float* __restrict__ asd_out,
    float* __restrict__ apts_out)
{
    const int h = blockIdx.y;
    const int i0 = blockIdx.x * 4;
    const int t = threadIdx.x;

    __shared__ float qs[4][32];   // [i][0:16]=q, [16:28]=rotated qp, pad
    __shared__ float sqq_s[4];
    __shared__ float dm_s[4];
    __shared__ float red[4][4];

    if (t < 128) {
        int i = t >> 5, c = t & 31;
        float v = 0.f;
        if (c < 16)      v = qb[(size_t)(i0 + i) * QCW + h * CH + c];
        else if (c < 28) v = qpb[(size_t)(i0 + i) * 144 + h * 12 + (c - 16)];
        qs[i][c] = v;
    } else if (t < 132) {
        int i = t - 128;
        sqq_s[i] = sqq_g[(size_t)(i0 + i) * NH + h];
        dm_s[i] = dmask[i0 + i];
    }
    const float hwv = log1pf(__expf(head_w[h])) * (1.0f / 6.0f);
    const float s1 = 0.17677669529663687f;  // sqrt(1/32)
    const size_t rowbase = ((size_t)h * LD + i0) * LS;
    __syncthreads();

    float4 sregv[4][2];
    float mx[4] = {-3.0e38f, -3.0e38f, -3.0e38f, -3.0e38f};

#pragma unroll
    for (int jc = 0; jc < 2; ++jc) {
        const int j = (jc * 256 + t) * 4;
        float4 sm4 = *(const float4*)(smask + j);
        float4 sqk4 = *(const float4*)(sqkT + (size_t)h * LS + j);

        // Burst-load all 16 k rows (independent 16B loads -> deep MLP)
        float4 kk[16];
#pragma unroll
        for (int c = 0; c < 16; ++c)
            kk[c] = *(const float4*)(kT + ((size_t)h * 16 + c) * LS + j);

        float4 qk4[4];
#pragma unroll
        for (int i = 0; i < 4; ++i) {
            const float4* q4 = (const float4*)&qs[i][0];
            float4 q0 = q4[0], q1 = q4[1], q2 = q4[2], q3 = q4[3];
            float4 a;
            a.x = q0.x * kk[0].x + q0.y * kk[1].x + q0.z * kk[2].x + q0.w * kk[3].x
                + q1.x * kk[4].x + q1.y * kk[5].x + q1.z * kk[6].x + q1.w * kk[7].x
                + q2.x * kk[8].x + q2.y * kk[9].x + q2.z * kk[10].x + q2.w * kk[11].x
                + q3.x * kk[12].x + q3.y * kk[13].x + q3.z * kk[14].x + q3.w * kk[15].x;
            a.y = q0.x * kk[0].y + q0.y * kk[1].y + q0.z * kk[2].y + q0.w * kk[3].y
                + q1.x * kk[4].y + q1.y * kk[5].y + q1.z * kk[6].y + q1.w * kk[7].y
                + q2.x * kk[8].y + q2.y * kk[9].y + q2.z * kk[10].y + q2.w * kk[11].y
                + q3.x * kk[12].y + q3.y * kk[13].y + q3.z * kk[14].y + q3.w * kk[15].y;
            a.z = q0.x * kk[0].z + q0.y * kk[1].z + q0.z * kk[2].z + q0.w * kk[3].z
                + q1.x * kk[4].z + q1.y * kk[5].z + q1.z * kk[6].z + q1.w * kk[7].z
                + q2.x * kk[8].z + q2.y * kk[9].z + q2.z * kk[10].z + q2.w * kk[11].z
                + q3.x * kk[12].z + q3.y * kk[13].z + q3.z * kk[14].z + q3.w * kk[15].z;
            a.w = q0.x * kk[0].w + q0.y * kk[1].w + q0.z * kk[2].w + q0.w * kk[3].w
                + q1.x * kk[4].w + q1.y * kk[5].w + q1.z * kk[6].w + q1.w * kk[7].w
                + q2.x * kk[8].w + q2.y * kk[9].w + q2.z * kk[10].w + q2.w * kk[11].w
                + q3.x * kk[12].w + q3.y * kk[13].w + q3.z * kk[14].w + q3.w * kk[15].w;
            qk4[i] = a;
        }

        // Burst-load all 12 kp rows
        float4 pp[12];
#pragma unroll
        for (int d = 0; d < 12; ++d)
            pp[d] = *(const float4*)(kpT + ((size_t)h * 12 + d) * LS + j);

        float4 dp4[4];
#pragma unroll
        for (int i = 0; i < 4; ++i) {
            const float4* r4 = (const float4*)&qs[i][16];
            float4 r0 = r4[0], r1 = r4[1], r2 = r4[2];
            float4 d;
            d.x = r0.x * pp[0].x + r0.y * pp[1].x + r0.z * pp[2].x + r0.w * pp[3].x
                + r1.x * pp[4].x + r1.y * pp[5].x + r1.z * pp[6].x + r1.w * pp[7].x
                + r2.x * pp[8].x + r2.y * pp[9].x + r2.z * pp[10].x + r2.w * pp[11].x;
            d.y = r0.x * pp[0].y + r0.y * pp[1].y + r0.z * pp[2].y + r0.w * pp[3].y
                + r1.x * pp[4].y + r1.y * pp[5].y + r1.z * pp[6].y + r1.w * pp[7].y
                + r2.x * pp[8].y + r2.y * pp[9].y + r2.z * pp[10].y + r2.w * pp[11].y;
            d.z = r0.x * pp[0].z + r0.y * pp[1].z + r0.z * pp[2].z + r0.w * pp[3].z
                + r1.x * pp[4].z + r1.y * pp[5].z + r1.z * pp[6].z + r1.w * pp[7].z
                + r2.x * pp[8].z + r2.y * pp[9].z + r2.z * pp[10].z + r2.w * pp[11].z;
            d.w = r0.x * pp[0].w + r0.y * pp[1].w + r0.z * pp[2].w + r0.w * pp[3].w
                + r1.x * pp[4].w + r1.y * pp[5].w + r1.z * pp[6].w + r1.w * pp[7].w
                + r2.x * pp[8].w + r2.y * pp[9].w + r2.z * pp[10].w + r2.w * pp[11].w;
            dp4[i] = d;
        }

#pragma unroll
        for (int i = 0; i < 4; ++i) {
            float sqq = sqq_s[i];
            float dm = dm_s[i];
            float4 qk, pt, g, logit;
            qk.x = qk4[i].x * s1; qk.y = qk4[i].y * s1;
            qk.z = qk4[i].z * s1; qk.w = qk4[i].w * s1;
            pt.x = -0.5f * hwv * (sqq + sqk4.x - 2.f * dp4[i].x);
            pt.y = -0.5f * hwv * (sqq + sqk4.y - 2.f * dp4[i].y);
            pt.z = -0.5f * hwv * (sqq + sqk4.z - 2.f * dp4[i].z);
            pt.w = -0.5f * hwv * (sqq + sqk4.w - 2.f * dp4[i].w);
            g.x = dm * sm4.x; g.y = dm * sm4.y; g.z = dm * sm4.z; g.w = dm * sm4.w;
            size_t idx = rowbase + (size_t)i * LS + j;
            f32x4 asd = {qk.x * g.x, qk.y * g.y, qk.z * g.z, qk.w * g.w};
            f32x4 apts = {pt.x * g.x, pt.y * g.y, pt.z * g.z, pt.w * g.w};
            __builtin_nontemporal_store(asd, (f32x4*)(asd_out + idx));
            __builtin_nontemporal_store(apts, (f32x4*)(apts_out + idx));
            logit.x = qk.x + pt.x + 1.0e9f * (g.x - 1.0f);
            logit.y = qk.y + pt.y + 1.0e9f * (g.y - 1.0f);
            logit.z = qk.z + pt.z + 1.0e9f * (g.z - 1.0f);
            logit.w = qk.w + pt.w + 1.0e9f * (g.w - 1.0f);
            sregv[i][jc] = logit;
            mx[i] = fmaxf(mx[i], fmaxf(fmaxf(logit.x, logit.y), fmaxf(logit.z, logit.w)));
        }
    }

    const int lane = t & 63, wid = t >> 6;
#pragma unroll
    for (int i = 0; i < 4; ++i) {
        float v = mx[i];
        for (int off = 32; off > 0; off >>= 1) v = fmaxf(v, __shfl_xor(v, off));
        if (lane == 0) red[wid][i] = v;
    }
    __syncthreads();
    float M[4], sum[4] = {0.f, 0.f, 0.f, 0.f};
#pragma unroll
    for (int i = 0; i < 4; ++i)
        M[i] = fmaxf(fmaxf(red[0][i], red[1][i]), fmaxf(red[2][i], red[3][i]));
    __syncthreads();

#pragma unroll
    for (int jc = 0; jc < 2; ++jc) {
#pragma unroll
        for (int i = 0; i < 4; ++i) {
            float4 e;
            e.x = __expf(sregv[i][jc].x - M[i]);
            e.y = __expf(sregv[i][jc].y - M[i]);
            e.z = __expf(sregv[i][jc].z - M[i]);
            e.w = __expf(sregv[i][jc].w - M[i]);
            sregv[i][jc] = e;
            sum[i] += e.x + e.y + e.z + e.w;
        }
    }
#pragma unroll
    for (int i = 0; i < 4; ++i) {
        float v = sum[i];
        for (int off = 32; off > 0; off >>= 1) v += __shfl_xor(v, off);
        if (lane == 0) red[wid][i] = v;
    }
    __syncthreads();
    float inv[4];
#pragma unroll
    for (int i = 0; i < 4; ++i)
        inv[i] = 1.0f / (red[0][i] + red[1][i] + red[2][i] + red[3][i]);

#pragma unroll
    for (int jc = 0; jc < 2; ++jc) {
        const int j = (jc * 256 + t) * 4;
#pragma unroll
        for (int i = 0; i < 4; ++i) {
            float4 e = sregv[i][jc];
            float4 o = make_float4(e.x * inv[i], e.y * inv[i], e.z * inv[i], e.w * inv[i]);
            *(float4*)(a_out + rowbase + (size_t)i * LS + j) = o;
        }
    }
}

// ---------------------------------------------------------------------------
// AV via MFMA, split-bf16. 512 threads = 8 waves; each wave owns a disjoint
// CONTIGUOUS 256-wide K-chunk (8 x 256 = LS = 2048). Partials reduced across
// waves in LDS (padded inner dim 13 -> conflict-free), wave 0 stores.
// No atomics, no memset prerequisite.
// ---------------------------------------------------------------------------
__global__ __launch_bounds__(512) void av_mfma_kernel(
    const float* __restrict__ a, const float* __restrict__ vAllT,
    float* __restrict__ o_buf, float* __restrict__ opt_buf)
{
    const int m0 = blockIdx.x * 16;
    const int h  = blockIdx.y;
    const int t = threadIdx.x;
    const int lane = t & 63;
    const int wid  = t >> 6;            // 0..7 -> K-chunk of 256
    const int row16 = lane & 15, kq = lane >> 4;

    const size_t kbase = (size_t)wid * 256 + kq * 8;
    const float* ap  = a     + ((size_t)h * LD + m0 + row16) * LS + kbase;
    const float* v0p = vAllT + ((size_t)h * 40 +  0 + row16) * LS + kbase;
    const float* v1p = vAllT + ((size_t)h * 40 + 16 + row16) * LS + kbase;
    const float* v2p = vAllT + ((size_t)h * 40 + 24 + row16) * LS + kbase;

    f32x4 acc0 = {0.f, 0.f, 0.f, 0.f};
    f32x4 acc1 = {0.f, 0.f, 0.f, 0.f};
    f32x4 acc2 = {0.f, 0.f, 0.f, 0.f};

#pragma unroll 2
    for (int kk = 0; kk < 256; kk += 32) {
        bf16x8 ah, al, bh, bl;
        split_frag(ap + kk, ah, al);

        split_frag(v0p + kk, bh, bl);
        acc0 = __builtin_amdgcn_mfma_f32_16x16x32_bf16(ah, bh, acc0, 0, 0, 0);
        acc0 = __builtin_amdgcn_mfma_f32_16x16x32_bf16(ah, bl, acc0, 0, 0, 0);
        acc0 = __builtin_amdgcn_mfma_f32_16x16x32_bf16(al, bh, acc0, 0, 0, 0);

        split_frag(v1p + kk, bh, bl);
        acc1 = __builtin_amdgcn_mfma_f32_16x16x32_bf16(ah, bh, acc1, 0, 0, 0);
        acc1 = __builtin_amdgcn_mfma_f32_16x16x32_bf16(ah, bl, acc1, 0, 0, 0);
        acc1 = __builtin_amdgcn_mfma_f32_16x16x32_bf16(al, bh, acc1, 0, 0, 0);

        split_frag(v2p + kk, bh, bl);
        acc2 = __builtin_amdgcn_mfma_f32_16x16x32_bf16(ah, bh, acc2, 0, 0, 0);
        acc2 = __builtin_amdgcn_mfma_f32_16x16x32_bf16(ah, bl, acc2, 0, 0, 0);
        acc2 = __builtin_amdgcn_mfma_f32_16x16x32_bf16(al, bh, acc2, 0, 0, 0);
    }

    // Cross-wave reduction in LDS. Inner dim padded to 13 (odd stride -> 2
    // lanes/bank for the lane-indexed access = conflict-free per m136).
    __shared__ float red[8][64][13];
#pragma unroll
    for (int r = 0; r < 4; ++r) {
        red[wid][lane][r]     = acc0[r];
        red[wid][lane][4 + r] = acc1[r];
        red[wid][lane][8 + r] = acc2[r];
    }
    __syncthreads();

    if (wid == 0) {
        float s[12];
#pragma unroll
        for (int r = 0; r < 12; ++r) {
            float v = red[0][lane][r];
#pragma unroll
            for (int w = 1; w < 8; ++w) v += red[w][lane][r];
            s[r] = v;
        }
        const int ib = m0 + kq * 4;
#pragma unroll
        for (int r = 0; r < 4; ++r) {
            const int i = ib + r;
            o_buf[(size_t)i * 192 + h * 16 + row16] = s[r];
            opt_buf[(size_t)i * 288 + h * 24 + row16] = s[4 + r];
            if (row16 >= 8)
                opt_buf[(size_t)i * 288 + h * 24 + 8 + row16] = s[8 + r];
        }
    }
}

// ---------------------------------------------------------------------------
// Finalize: cat = [o(192) | x(96) | y(96) | z(96) | norm(96)]
// ---------------------------------------------------------------------------
__global__ __launch_bounds__(192) void finalize_kernel(
    const float* __restrict__ o_buf, const float* __restrict__ opt_buf,
    const float* __restrict__ Rd, const float* __restrict__ td,
    float* __restrict__ cat)
{
    const int i = blockIdx.x, t = threadIdx.x;
    cat[i * 576 + t] = o_buf[i * 192 + t];
    if (t < 96) {
        const float* op = opt_buf + i * 288 + t * 3;
        float x = op[0] - td[i * 3 + 0];
        float y = op[1] - td[i * 3 + 1];
        float z = op[2] - td[i * 3 + 2];
        const float* R = Rd + i * 9;
        float rx = R[0] * x + R[3] * y + R[6] * z;
        float ry = R[1] * x + R[4] * y + R[7] * z;
        float rz = R[2] * x + R[5] * y + R[8] * z;
        float* cc = cat + i * 576 + 192;
        cc[t] = rx;
        cc[96 + t] = ry;
        cc[192 + t] = rz;
        cc[288 + t] = sqrtf(rx * rx + ry * ry + rz * rz + 1e-8f);
    }
}

// ---------------------------------------------------------------------------
extern "C" void kernel_launch(void* const* d_in, const int* in_sizes, int n_in,
                              void* d_out, int out_size, void* d_ws, size_t ws_size,
                              hipStream_t stream)
{
    (void)in_sizes; (void)n_in; (void)out_size; (void)ws_size;
    const float* s_dst    = (const float*)d_in[0];
    const float* s_src    = (const float*)d_in[1];
    const float* R_dst    = (const float*)d_in[2];
    const float* t_dst    = (const float*)d_in[3];
    const float* R_src    = (const float*)d_in[4];
    const float* t_src    = (const float*)d_in[5];
    const float* dst_mask = (const float*)d_in[6];
    const float* src_mask = (const float*)d_in[7];
    const float* W_q      = (const float*)d_in[8];
    const float* W_kv     = (const float*)d_in[9];
    const float* W_qp     = (const float*)d_in[10];
    const float* W_kvp    = (const float*)d_in[11];
    const float* W_out    = (const float*)d_in[12];
    const float* b_out    = (const float*)d_in[13];
    const float* head_w   = (const float*)d_in[14];

    float* ws = (float*)d_ws;
    float* qcat    = ws;                    // 512*336    = 172032
    float* kvcat   = qcat    + 172032;      // 2048*816   = 1671168
    float* qp_rot  = kvcat   + 1671168;     // 512*144    = 73728
    float* sq_q    = qp_rot  + 73728;       // 512*12     = 6144
    float* o_buf   = sq_q    + 6144;        // 512*192    = 98304
    float* opt_buf = o_buf   + 98304;       // 512*288    = 147456
    float* cat_buf = opt_buf + 147456;      // 512*576    = 294912
    float* kT      = cat_buf + 294912;      // 12*16*2048 = 393216
    float* vAllT   = kT      + 393216;      // 12*40*2048 = 983040
    float* kpT     = vAllT   + 983040;      // 12*12*2048 = 294912
    float* sqkT    = kpT     + 294912;      // 12*2048    = 24576
    float* Wt_qc   = sqkT    + 24576;       // 336*384    = 129024
    float* Wt_kvc  = Wt_qc   + 129024;      // 816*384    = 313344
    float* Wt_out  = Wt_kvc  + 313344;      // 384*576    = 221184

    float* out_s    = (float*)d_out;              // 512*384
    float* out_a    = out_s    + 196608;          // 12*512*2048
    float* out_asd  = out_a    + 12582912;
    float* out_apts = out_asd  + 12582912;

    // All weight transposes in one launch
    transpose_w_all_kernel<<<dim3(660), dim3(256), 0, stream>>>(
        W_q, W_kv, W_qp, W_kvp, W_out, Wt_qc, Wt_kvc, Wt_out);
    // Projections via MFMA split-bf16
    mfma_gemm_bt_kernel<<<dim3(16, 11), dim3(64), 0, stream>>>(s_dst, Wt_qc,  nullptr, qcat,  LD, QCW, CS);
    mfma_gemm_bt_kernel<<<dim3(64, 26), dim3(64), 0, stream>>>(s_src, Wt_kvc, nullptr, kvcat, LS, KVW, CS);
    // Fused prep: rot_dst + rot_src + transpose_kv (coalesced writes)
    prep_kernel<<<dim3(32, 13), dim3(256), 0, stream>>>(
        qcat, kvcat, R_dst, t_dst, R_src, t_src,
        qp_rot, sq_q, kT, vAllT, kpT, sqkT);
    // Scores + softmax (+ a_sd, a_pts, a outputs)
    score_softmax_kernel<<<dim3(LD / 4, NH), dim3(256), 0, stream>>>(
        qcat, kT, qp_rot, kpT, sq_q, sqkT, dst_mask, src_mask, head_w,
        out_a, out_asd, out_apts);
    // MFMA AV: 8-wave blocks, K split across waves (8 x 256 = 2048), LDS reduce
    av_mfma_kernel<<<dim3(LD / 16, NH), dim3(512), 0, stream>>>(out_a, vAllT, o_buf, opt_buf);
    // Inverse rotation, norms, concat
    finalize_kernel<<<LD, 192, 0, stream>>>(o_buf, opt_buf, R_dst, t_dst, cat_buf);
    // Output projection via MFMA split-bf16 (+bias)
    mfma_gemm_bt_kernel<<<dim3(16, 12), dim3(64), 0, stream>>>(cat_buf, Wt_out, b_out, out_s, LD, CS, 576);
}

// Round 4
// 262.757 us; speedup vs baseline: 1.2627x; 1.1637x over previous
//
#include <hip/hip_runtime.h>
#include <hip/hip_bf16.h>

// Problem constants
#define LD 512
#define LS 2048
#define CS 384
#define CH 16
#define NH 12
#define PQ 4
#define PV 8
#define QCW 336   // packed [q(192) | qp(144)] row width
#define KVW 816   // packed [kv(384) | kvp(432)] row width

typedef __bf16 bf16x8 __attribute__((ext_vector_type(8)));
typedef float  f32x4  __attribute__((ext_vector_type(4)));

// ---------------------------------------------------------------------------
// Split an 8-float run into bf16 hi/lo fragments (hi + lo ~= fp32 value).
// ---------------------------------------------------------------------------
__device__ inline void split_frag(const float* __restrict__ p, bf16x8& hi, bf16x8& lo)
{
    float4 x = *(const float4*)p;
    float4 y = *(const float4*)(p + 4);
    float f[8] = {x.x, x.y, x.z, x.w, y.x, y.y, y.z, y.w};
#pragma unroll
    for (int e = 0; e < 8; ++e) {
        __bf16 h = (__bf16)f[e];
        hi[e] = h;
        lo[e] = (__bf16)(f[e] - (float)h);
    }
}

// ---------------------------------------------------------------------------
// Same, but gathers 8 elements column-wise from W[k][n] (stride = row width).
// Element e = W[(k0+e)*stride + ncol] == Bt[ncol][k0+e]. Coalesced across
// lanes (16 consecutive ncol per 4B load -> 64B segments), W is L2-resident.
// ---------------------------------------------------------------------------
__device__ inline void split_frag_w(const float* __restrict__ Wp, int stride,
                                    bf16x8& hi, bf16x8& lo)
{
    float f[8];
#pragma unroll
    for (int e = 0; e < 8; ++e) f[e] = Wp[(size_t)e * stride];
#pragma unroll
    for (int e = 0; e < 8; ++e) {
        __bf16 h = (__bf16)f[e];
        hi[e] = h;
        lo[e] = (__bf16)(f[e] - (float)h);
    }
}

// ---------------------------------------------------------------------------
// MERGED projection GEMMs (qcat + kvcat) in ONE launch, reading the weight
// matrices DIRECTLY (transposed indexing) -- no pre-transpose stage.
//   blocks [0,176):    qcat  = s_dst @ [W_q | W_qp]    M=512, N=336, K=384
//   blocks [176,1840): kvcat = s_src @ [W_kv | W_kvp]  M=2048, N=816, K=384
// Per-block n-segment lookup picks the right W and column offset; 32-wide
// n-tiles never straddle a segment boundary (192 = 6*32, 384 = 12*32).
// ---------------------------------------------------------------------------
__global__ __launch_bounds__(64) void proj_gemm_kernel(
    const float* __restrict__ s_dst, const float* __restrict__ s_src,
    const float* __restrict__ W_q, const float* __restrict__ W_qp,
    const float* __restrict__ W_kv, const float* __restrict__ W_kvp,
    float* __restrict__ qcat, float* __restrict__ kvcat)
{
    const float* A; float* C; int N, m0, n0, Nw; const float* Wsrc; int ncol0;
    if (blockIdx.x < 176) {
        int b = blockIdx.x;
        A = s_dst; C = qcat; N = QCW;
        m0 = (b & 15) * 32; n0 = (b >> 4) * 32;
        if (n0 < 192) { Wsrc = W_q;  Nw = 192; ncol0 = n0; }
        else          { Wsrc = W_qp; Nw = 144; ncol0 = n0 - 192; }
    } else {
        int b = blockIdx.x - 176;
        A = s_src; C = kvcat; N = KVW;
        m0 = (b & 63) * 32; n0 = (b >> 6) * 32;
        if (n0 < 384) { Wsrc = W_kv;  Nw = 384; ncol0 = n0; }
        else          { Wsrc = W_kvp; Nw = 432; ncol0 = n0 - 384; }
    }
    const int lane = threadIdx.x;
    const int row16 = lane & 15, kq = lane >> 4;
    const int K = CS;

    const float* ap0 = A + (size_t)(m0 + row16) * K + kq * 8;
    const float* ap1 = ap0 + (size_t)16 * K;
    const float* wp0 = Wsrc + (size_t)(kq * 8) * Nw + ncol0 + row16;
    const float* wp1 = wp0 + 16;
    const bool n1ok = (n0 + 16) < N;

    f32x4 acc00 = {0.f, 0.f, 0.f, 0.f};
    f32x4 acc10 = {0.f, 0.f, 0.f, 0.f};
    f32x4 acc01 = {0.f, 0.f, 0.f, 0.f};
    f32x4 acc11 = {0.f, 0.f, 0.f, 0.f};

    for (int k = 0; k < K; k += 32) {
        bf16x8 a0h, a0l, a1h, a1l, b0h, b0l, b1h, b1l;
        split_frag(ap0 + k, a0h, a0l);
        split_frag(ap1 + k, a1h, a1l);
        split_frag_w(wp0 + (size_t)k * Nw, Nw, b0h, b0l);
        acc00 = __builtin_amdgcn_mfma_f32_16x16x32_bf16(a0h, b0h, acc00, 0, 0, 0);
        acc00 = __builtin_amdgcn_mfma_f32_16x16x32_bf16(a0h, b0l, acc00, 0, 0, 0);
        acc00 = __builtin_amdgcn_mfma_f32_16x16x32_bf16(a0l, b0h, acc00, 0, 0, 0);
        acc10 = __builtin_amdgcn_mfma_f32_16x16x32_bf16(a1h, b0h, acc10, 0, 0, 0);
        acc10 = __builtin_amdgcn_mfma_f32_16x16x32_bf16(a1h, b0l, acc10, 0, 0, 0);
        acc10 = __builtin_amdgcn_mfma_f32_16x16x32_bf16(a1l, b0h, acc10, 0, 0, 0);
        if (n1ok) {
            split_frag_w(wp1 + (size_t)k * Nw, Nw, b1h, b1l);
            acc01 = __builtin_amdgcn_mfma_f32_16x16x32_bf16(a0h, b1h, acc01, 0, 0, 0);
            acc01 = __builtin_amdgcn_mfma_f32_16x16x32_bf16(a0h, b1l, acc01, 0, 0, 0);
            acc01 = __builtin_amdgcn_mfma_f32_16x16x32_bf16(a0l, b1h, acc01, 0, 0, 0);
            acc11 = __builtin_amdgcn_mfma_f32_16x16x32_bf16(a1h, b1h, acc11, 0, 0, 0);
            acc11 = __builtin_amdgcn_mfma_f32_16x16x32_bf16(a1h, b1l, acc11, 0, 0, 0);
            acc11 = __builtin_amdgcn_mfma_f32_16x16x32_bf16(a1l, b1h, acc11, 0, 0, 0);
        }
    }

#pragma unroll
    for (int r = 0; r < 4; ++r) {
        const int mA = m0 + kq * 4 + r;
        const int mB = mA + 16;
        C[(size_t)mA * N + n0 + row16] = acc00[r];
        C[(size_t)mB * N + n0 + row16] = acc10[r];
        if (n1ok) {
            C[(size_t)mA * N + n0 + 16 + row16] = acc01[r];
            C[(size_t)mB * N + n0 + 16 + row16] = acc11[r];
        }
    }
}

// ---------------------------------------------------------------------------
// Output GEMM: out_s = cat_buf @ W_out + b_out. Direct-W reads (no Wt_out).
// M=512, N=384, K=576. Grid (16, 12).
// ---------------------------------------------------------------------------
__global__ __launch_bounds__(64) void out_gemm_kernel(
    const float* __restrict__ A, const float* __restrict__ W_out,
    const float* __restrict__ bias, float* __restrict__ C)
{
    const int m0 = blockIdx.x * 32;
    const int n0 = blockIdx.y * 32;
    const int lane = threadIdx.x;
    const int row16 = lane & 15, kq = lane >> 4;
    const int K = 576, N = CS, Nw = CS;

    const float* ap0 = A + (size_t)(m0 + row16) * K + kq * 8;
    const float* ap1 = ap0 + (size_t)16 * K;
    const float* wp0 = W_out + (size_t)(kq * 8) * Nw + n0 + row16;
    const float* wp1 = wp0 + 16;

    f32x4 acc00 = {0.f, 0.f, 0.f, 0.f};
    f32x4 acc10 = {0.f, 0.f, 0.f, 0.f};
    f32x4 acc01 = {0.f, 0.f, 0.f, 0.f};
    f32x4 acc11 = {0.f, 0.f, 0.f, 0.f};

    for (int k = 0; k < K; k += 32) {
        bf16x8 a0h, a0l, a1h, a1l, b0h, b0l, b1h, b1l;
        split_frag(ap0 + k, a0h, a0l);
        split_frag(ap1 + k, a1h, a1l);
        split_frag_w(wp0 + (size_t)k * Nw, Nw, b0h, b0l);
        acc00 = __builtin_amdgcn_mfma_f32_16x16x32_bf16(a0h, b0h, acc00, 0, 0, 0);
        acc00 = __builtin_amdgcn_mfma_f32_16x16x32_bf16(a0h, b0l, acc00, 0, 0, 0);
        acc00 = __builtin_amdgcn_mfma_f32_16x16x32_bf16(a0l, b0h, acc00, 0, 0, 0);
        acc10 = __builtin_amdgcn_mfma_f32_16x16x32_bf16(a1h, b0h, acc10, 0, 0, 0);
        acc10 = __builtin_amdgcn_mfma_f32_16x16x32_bf16(a1h, b0l, acc10, 0, 0, 0);
        acc10 = __builtin_amdgcn_mfma_f32_16x16x32_bf16(a1l, b0h, acc10, 0, 0, 0);
        split_frag_w(wp1 + (size_t)k * Nw, Nw, b1h, b1l);
        acc01 = __builtin_amdgcn_mfma_f32_16x16x32_bf16(a0h, b1h, acc01, 0, 0, 0);
        acc01 = __builtin_amdgcn_mfma_f32_16x16x32_bf16(a0h, b1l, acc01, 0, 0, 0);
        acc01 = __builtin_amdgcn_mfma_f32_16x16x32_bf16(a0l, b1h, acc01, 0, 0, 0);
        acc11 = __builtin_amdgcn_mfma_f32_16x16x32_bf16(a1h, b1h, acc11, 0, 0, 0);
        acc11 = __builtin_amdgcn_mfma_f32_16x16x32_bf16(a1h, b1l, acc11, 0, 0, 0);
        acc11 = __builtin_amdgcn_mfma_f32_16x16x32_bf16(a1l, b1h, acc11, 0, 0, 0);
    }

    const float bv0 = bias[n0 + row16];
    const float bv1 = bias[n0 + 16 + row16];
#pragma unroll
    for (int r = 0; r < 4; ++r) {
        const int mA = m0 + kq * 4 + r;
        const int mB = mA + 16;
        C[(size_t)mA * N + n0 + row16] = acc00[r] + bv0;
        C[(size_t)mB * N + n0 + row16] = acc10[r] + bv0;
        C[(size_t)mA * N + n0 + 16 + row16] = acc01[r] + bv1;
        C[(size_t)mB * N + n0 + 16 + row16] = acc11[r] + bv1;
    }
}

// ---------------------------------------------------------------------------
// FUSED prep: rot_src + transpose_kv + rot_dst in one launch.
// grid (32, 13), 256 threads. (unchanged from round 3)
// ---------------------------------------------------------------------------
__global__ __launch_bounds__(256) void prep_kernel(
    const float* __restrict__ qcat, const float* __restrict__ kvcat,
    const float* __restrict__ Rd, const float* __restrict__ td,
    const float* __restrict__ Rs, const float* __restrict__ ts,
    float* __restrict__ qp_rot, float* __restrict__ sqq,
    float* __restrict__ kT, float* __restrict__ vAllT,
    float* __restrict__ kpT, float* __restrict__ sqkT)
{
    const int t = threadIdx.x;
    if (blockIdx.y < NH) {
        const int h = blockIdx.y, j0 = blockIdx.x * 64;
        __shared__ float tile[64][33];
        __shared__ float ot[36][64];
        __shared__ float nrm[64][4];
        __shared__ float rt[64][12];

#pragma unroll
        for (int s = 0; s < 3; ++s) {
            int ld = t + s * 256;
            int jl = ld / 12, q = ld % 12;
            rt[jl][q] = (q < 9) ? Rs[(size_t)(j0 + jl) * 9 + q]
                                : ts[(size_t)(j0 + jl) * 3 + (q - 9)];
        }
#pragma unroll
        for (int r = 0; r < 2; ++r) {
            int f = t + r * 256;
            int jl = f >> 3, c4 = (f & 7) * 4;
            float4 v = *(const float4*)(kvcat + (size_t)(j0 + jl) * KVW + h * 32 + c4);
            tile[jl][c4 + 0] = v.x;
            tile[jl][c4 + 1] = v.y;
            tile[jl][c4 + 2] = v.z;
            tile[jl][c4 + 3] = v.w;
        }
        __syncthreads();

        {
            const int jl = t & 63, cr = t >> 6;
#pragma unroll
            for (int cg = 0; cg < 8; ++cg) {
                int c = cg * 4 + cr;
                float v = tile[jl][c];
                if (c < 16) kT[((size_t)h * 16 + c) * LS + j0 + jl] = v;
                else        vAllT[((size_t)h * 40 + (c - 16)) * LS + j0 + jl] = v;
            }
        }

#pragma unroll
        for (int s = 0; s < 3; ++s) {
            int u = t + s * 256;
            int jl = u / 12, p = u % 12;
            const float* src = kvcat + (size_t)(j0 + jl) * KVW + 384 + h * 12 + p;
            float x = src[0], y = src[144], z = src[288];
            const float* R = &rt[jl][0];
            float rx = R[0] * x + R[1] * y + R[2] * z + R[9];
            float ry = R[3] * x + R[4] * y + R[5] * z + R[10];
            float rz = R[6] * x + R[7] * y + R[8] * z + R[11];
            if (p < 4) {
                ot[p * 3 + 0][jl] = rx;
                ot[p * 3 + 1][jl] = ry;
                ot[p * 3 + 2][jl] = rz;
                nrm[jl][p] = rx * rx + ry * ry + rz * rz;
            } else {
                int r0 = 12 + (p - 4) * 3;
                ot[r0 + 0][jl] = rx;
                ot[r0 + 1][jl] = ry;
                ot[r0 + 2][jl] = rz;
            }
        }
        __syncthreads();

#pragma unroll
        for (int w = 0; w < 9; ++w) {
            int idx = t + w * 256;
            int row = idx >> 6, jl = idx & 63;
            float v = ot[row][jl];
            if (row < 12) kpT[((size_t)h * 12 + row) * LS + j0 + jl] = v;
            else          vAllT[((size_t)h * 40 + 16 + (row - 12)) * LS + j0 + jl] = v;
        }
        if (t < 64)
            sqkT[(size_t)h * LS + j0 + t] = nrm[t][0] + nrm[t][1] + nrm[t][2] + nrm[t][3];
    } else {
        const int i0 = blockIdx.x * 16;
        __shared__ float part[16][48];
        __shared__ float rtd[16][12];
        if (t < 192) {
            int il = t / 12, q = t % 12;
            rtd[il][q] = (q < 9) ? Rd[(size_t)(i0 + il) * 9 + q]
                                 : td[(size_t)(i0 + il) * 3 + (q - 9)];
        }
        __syncthreads();
#pragma unroll
        for (int s = 0; s < 3; ++s) {
            int u = t + s * 256;
            int il = u / 48, pt = u % 48;
            int i = i0 + il;
            float x = qcat[(size_t)i * QCW + 192 + pt];
            float y = qcat[(size_t)i * QCW + 240 + pt];
            float z = qcat[(size_t)i * QCW + 288 + pt];
            const float* R = &rtd[il][0];
            float rx = R[0] * x + R[1] * y + R[2] * z + R[9];
            float ry = R[3] * x + R[4] * y + R[5] * z + R[10];
            float rz = R[6] * x + R[7] * y + R[8] * z + R[11];
            qp_rot[(size_t)i * 144 + pt * 3 + 0] = rx;
            qp_rot[(size_t)i * 144 + pt * 3 + 1] = ry;
            qp_rot[(size_t)i * 144 + pt * 3 + 2] = rz;
            part[il][pt] = rx * rx + ry * ry + rz * rz;
        }
        __syncthreads();
        if (t < 192) {
            int il = t / 12, hh = t % 12;
            sqq[(size_t)(i0 + il) * NH + hh] =
                part[il][hh * 4] + part[il][hh * 4 + 1] +
                part[il][hh * 4 + 2] + part[il][hh * 4 + 3];
        }
    }
}

// ---------------------------------------------------------------------------
// Scores + softmax. (unchanged from round 3)
// ---------------------------------------------------------------------------
__global__ __launch_bounds__(256) void score_softmax_kernel(
    const float* __restrict__ qb, const float* __restrict__ kT,
    const float* __restrict__ qpb, const float* __restrict__ kpT,
    const float* __restrict__ sqq_g, const float* __restrict__ sqkT,
    const float* __restrict__ dmask, const float* __restrict__ smask,
    const float* __restrict__ head_w,
    float* __restrict__ a_out, float* __restrict__ asd_out,
    float* __restrict__ apts_out)
{
    const int h = blockIdx.y;
    const int i0 = blockIdx.x * 4;
    const int t = threadIdx.x;

    __shared__ float qs[4][32];
    __shared__ float sqq_s[4];
    __shared__ float dm_s[4];
    __shared__ float red[4][4];

    if (t < 128) {
        int i = t >> 5, c = t & 31;
        float v = 0.f;
        if (c < 16)      v = qb[(size_t)(i0 + i) * QCW + h * CH + c];
        else if (c < 28) v = qpb[(size_t)(i0 + i) * 144 + h * 12 + (c - 16)];
        qs[i][c] = v;
    } else if (t < 132) {
        int i = t - 128;
        sqq_s[i] = sqq_g[(size_t)(i0 + i) * NH + h];
        dm_s[i] = dmask[i0 + i];
    }
    const float hwv = log1pf(__expf(head_w[h])) * (1.0f / 6.0f);
    const float s1 = 0.17677669529663687f;  // sqrt(1/32)
    const size_t rowbase = ((size_t)h * LD + i0) * LS;
    __syncthreads();

    float4 sregv[4][2];
    float mx[4] = {-3.0e38f, -3.0e38f, -3.0e38f, -3.0e38f};

#pragma unroll
    for (int jc = 0; jc < 2; ++jc) {
        const int j = (jc * 256 + t) * 4;
        float4 sm4 = *(const float4*)(smask + j);
        float4 sqk4 = *(const float4*)(sqkT + (size_t)h * LS + j);

        float4 kk[16];
#pragma unroll
        for (int c = 0; c < 16; ++c)
            kk[c] = *(const float4*)(kT + ((size_t)h * 16 + c) * LS + j);

        float4 qk4[4];
#pragma unroll
        for (int i = 0; i < 4; ++i) {
            const float4* q4 = (const float4*)&qs[i][0];
            float4 q0 = q4[0], q1 = q4[1], q2 = q4[2], q3 = q4[3];
            float4 a;
            a.x = q0.x * kk[0].x + q0.y * kk[1].x + q0.z * kk[2].x + q0.w * kk[3].x
                + q1.x * kk[4].x + q1.y * kk[5].x + q1.z * kk[6].x + q1.w * kk[7].x
                + q2.x * kk[8].x + q2.y * kk[9].x + q2.z * kk[10].x + q2.w * kk[11].x
                + q3.x * kk[12].x + q3.y * kk[13].x + q3.z * kk[14].x + q3.w * kk[15].x;
            a.y = q0.x * kk[0].y + q0.y * kk[1].y + q0.z * kk[2].y + q0.w * kk[3].y
                + q1.x * kk[4].y + q1.y * kk[5].y + q1.z * kk[6].y + q1.w * kk[7].y
                + q2.x * kk[8].y + q2.y * kk[9].y + q2.z * kk[10].y + q2.w * kk[11].y
                + q3.x * kk[12].y + q3.y * kk[13].y + q3.z * kk[14].y + q3.w * kk[15].y;
            a.z = q0.x * kk[0].z + q0.y * kk[1].z + q0.z * kk[2].z + q0.w * kk[3].z
                + q1.x * kk[4].z + q1.y * kk[5].z + q1.z * kk[6].z + q1.w * kk[7].z
                + q2.x * kk[8].z + q2.y * kk[9].z + q2.z * kk[10].z + q2.w * kk[11].z
                + q3.x * kk[12].z + q3.y * kk[13].z + q3.z * kk[14].z + q3.w * kk[15].z;
            a.w = q0.x * kk[0].w + q0.y * kk[1].w + q0.z * kk[2].w + q0.w * kk[3].w
                + q1.x * kk[4].w + q1.y * kk[5].w + q1.z * kk[6].w + q1.w * kk[7].w
                + q2.x * kk[8].w + q2.y * kk[9].w + q2.z * kk[10].w + q2.w * kk[11].w
                + q3.x * kk[12].w + q3.y * kk[13].w + q3.z * kk[14].w + q3.w * kk[15].w;
            qk4[i] = a;
        }

        float4 pp[12];
#pragma unroll
        for (int d = 0; d < 12; ++d)
            pp[d] = *(const float4*)(kpT + ((size_t)h * 12 + d) * LS + j);

        float4 dp4[4];
#pragma unroll
        for (int i = 0; i < 4; ++i) {
            const float4* r4 = (const float4*)&qs[i][16];
            float4 r0 = r4[0], r1 = r4[1], r2 = r4[2];
            float4 d;
            d.x = r0.x * pp[0].x + r0.y * pp[1].x + r0.z * pp[2].x + r0.w * pp[3].x
                + r1.x * pp[4].x + r1.y * pp[5].x + r1.z * pp[6].x + r1.w * pp[7].x
                + r2.x * pp[8].x + r2.y * pp[9].x + r2.z * pp[10].x + r2.w * pp[11].x;
            d.y = r0.x * pp[0].y + r0.y * pp[1].y + r0.z * pp[2].y + r0.w * pp[3].y
                + r1.x * pp[4].y + r1.y * pp[5].y + r1.z * pp[6].y + r1.w * pp[7].y
                + r2.x * pp[8].y + r2.y * pp[9].y + r2.z * pp[10].y + r2.w * pp[11].y;
            d.z = r0.x * pp[0].z + r0.y * pp[1].z + r0.z * pp[2].z + r0.w * pp[3].z
                + r1.x * pp[4].z + r1.y * pp[5].z + r1.z * pp[6].z + r1.w * pp[7].z
                + r2.x * pp[8].z + r2.y * pp[9].z + r2.z * pp[10].z + r2.w * pp[11].z;
            d.w = r0.x * pp[0].w + r0.y * pp[1].w + r0.z * pp[2].w + r0.w * pp[3].w
                + r1.x * pp[4].w + r1.y * pp[5].w + r1.z * pp[6].w + r1.w * pp[7].w
                + r2.x * pp[8].w + r2.y * pp[9].w + r2.z * pp[10].w + r2.w * pp[11].w;
            dp4[i] = d;
        }

#pragma unroll
        for (int i = 0; i < 4; ++i) {
            float sqq = sqq_s[i];
            float dm = dm_s[i];
            float4 qk, pt, g, logit;
            qk.x = qk4[i].x * s1; qk.y = qk4[i].y * s1;
            qk.z = qk4[i].z * s1; qk.w = qk4[i].w * s1;
            pt.x = -0.5f * hwv * (sqq + sqk4.x - 2.f * dp4[i].x);
            pt.y = -0.5f * hwv * (sqq + sqk4.y - 2.f * dp4[i].y);
            pt.z = -0.5f * hwv * (sqq + sqk4.z - 2.f * dp4[i].z);
            pt.w = -0.5f * hwv * (sqq + sqk4.w - 2.f * dp4[i].w);
            g.x = dm * sm4.x; g.y = dm * sm4.y; g.z = dm * sm4.z; g.w = dm * sm4.w;
            size_t idx = rowbase + (size_t)i * LS + j;
            f32x4 asd = {qk.x * g.x, qk.y * g.y, qk.z * g.z, qk.w * g.w};
            f32x4 apts = {pt.x * g.x, pt.y * g.y, pt.z * g.z, pt.w * g.w};
            __builtin_nontemporal_store(asd, (f32x4*)(asd_out + idx));
            __builtin_nontemporal_store(apts, (f32x4*)(apts_out + idx));
            logit.x = qk.x + pt.x + 1.0e9f * (g.x - 1.0f);
            logit.y = qk.y + pt.y + 1.0e9f * (g.y - 1.0f);
            logit.z = qk.z + pt.z + 1.0e9f * (g.z - 1.0f);
            logit.w = qk.w + pt.w + 1.0e9f * (g.w - 1.0f);
            sregv[i][jc] = logit;
            mx[i] = fmaxf(mx[i], fmaxf(fmaxf(logit.x, logit.y), fmaxf(logit.z, logit.w)));
        }
    }

    const int lane = t & 63, wid = t >> 6;
#pragma unroll
    for (int i = 0; i < 4; ++i) {
        float v = mx[i];
        for (int off = 32; off > 0; off >>= 1) v = fmaxf(v, __shfl_xor(v, off));
        if (lane == 0) red[wid][i] = v;
    }
    __syncthreads();
    float M[4], sum[4] = {0.f, 0.f, 0.f, 0.f};
#pragma unroll
    for (int i = 0; i < 4; ++i)
        M[i] = fmaxf(fmaxf(red[0][i], red[1][i]), fmaxf(red[2][i], red[3][i]));
    __syncthreads();

#pragma unroll
    for (int jc = 0; jc < 2; ++jc) {
#pragma unroll
        for (int i = 0; i < 4; ++i) {
            float4 e;
            e.x = __expf(sregv[i][jc].x - M[i]);
            e.y = __expf(sregv[i][jc].y - M[i]);
            e.z = __expf(sregv[i][jc].z - M[i]);
            e.w = __expf(sregv[i][jc].w - M[i]);
            sregv[i][jc] = e;
            sum[i] += e.x + e.y + e.z + e.w;
        }
    }
#pragma unroll
    for (int i = 0; i < 4; ++i) {
        float v = sum[i];
        for (int off = 32; off > 0; off >>= 1) v += __shfl_xor(v, off);
        if (lane == 0) red[wid][i] = v;
    }
    __syncthreads();
    float inv[4];
#pragma unroll
    for (int i = 0; i < 4; ++i)
        inv[i] = 1.0f / (red[0][i] + red[1][i] + red[2][i] + red[3][i]);

#pragma unroll
    for (int jc = 0; jc < 2; ++jc) {
        const int j = (jc * 256 + t) * 4;
#pragma unroll
        for (int i = 0; i < 4; ++i) {
            float4 e = sregv[i][jc];
            float4 o = make_float4(e.x * inv[i], e.y * inv[i], e.z * inv[i], e.w * inv[i]);
            *(float4*)(a_out + rowbase + (size_t)i * LS + j) = o;
        }
    }
}

// ---------------------------------------------------------------------------
// AV via MFMA, split-bf16. (unchanged from round 3)
// ---------------------------------------------------------------------------
__global__ __launch_bounds__(512) void av_mfma_kernel(
    const float* __restrict__ a, const float* __restrict__ vAllT,
    float* __restrict__ o_buf, float* __restrict__ opt_buf)
{
    const int m0 = blockIdx.x * 16;
    const int h  = blockIdx.y;
    const int t = threadIdx.x;
    const int lane = t & 63;
    const int wid  = t >> 6;
    const int row16 = lane & 15, kq = lane >> 4;

    const size_t kbase = (size_t)wid * 256 + kq * 8;
    const float* ap  = a     + ((size_t)h * LD + m0 + row16) * LS + kbase;
    const float* v0p = vAllT + ((size_t)h * 40 +  0 + row16) * LS + kbase;
    const float* v1p = vAllT + ((size_t)h * 40 + 16 + row16) * LS + kbase;
    const float* v2p = vAllT + ((size_t)h * 40 + 24 + row16) * LS + kbase;

    f32x4 acc0 = {0.f, 0.f, 0.f, 0.f};
    f32x4 acc1 = {0.f, 0.f, 0.f, 0.f};
    f32x4 acc2 = {0.f, 0.f, 0.f, 0.f};

#pragma unroll 2
    for (int kk = 0; kk < 256; kk += 32) {
        bf16x8 ah, al, bh, bl;
        split_frag(ap + kk, ah, al);

        split_frag(v0p + kk, bh, bl);
        acc0 = __builtin_amdgcn_mfma_f32_16x16x32_bf16(ah, bh, acc0, 0, 0, 0);
        acc0 = __builtin_amdgcn_mfma_f32_16x16x32_bf16(ah, bl, acc0, 0, 0, 0);
        acc0 = __builtin_amdgcn_mfma_f32_16x16x32_bf16(al, bh, acc0, 0, 0, 0);

        split_frag(v1p + kk, bh, bl);
        acc1 = __builtin_amdgcn_mfma_f32_16x16x32_bf16(ah, bh, acc1, 0, 0, 0);
        acc1 = __builtin_amdgcn_mfma_f32_16x16x32_bf16(ah, bl, acc1, 0, 0, 0);
        acc1 = __builtin_amdgcn_mfma_f32_16x16x32_bf16(al, bh, acc1, 0, 0, 0);

        split_frag(v2p + kk, bh, bl);
        acc2 = __builtin_amdgcn_mfma_f32_16x16x32_bf16(ah, bh, acc2, 0, 0, 0);
        acc2 = __builtin_amdgcn_mfma_f32_16x16x32_bf16(ah, bl, acc2, 0, 0, 0);
        acc2 = __builtin_amdgcn_mfma_f32_16x16x32_bf16(al, bh, acc2, 0, 0, 0);
    }

    __shared__ float red[8][64][13];
#pragma unroll
    for (int r = 0; r < 4; ++r) {
        red[wid][lane][r]     = acc0[r];
        red[wid][lane][4 + r] = acc1[r];
        red[wid][lane][8 + r] = acc2[r];
    }
    __syncthreads();

    if (wid == 0) {
        float s[12];
#pragma unroll
        for (int r = 0; r < 12; ++r) {
            float v = red[0][lane][r];
#pragma unroll
            for (int w = 1; w < 8; ++w) v += red[w][lane][r];
            s[r] = v;
        }
        const int ib = m0 + kq * 4;
#pragma unroll
        for (int r = 0; r < 4; ++r) {
            const int i = ib + r;
            o_buf[(size_t)i * 192 + h * 16 + row16] = s[r];
            opt_buf[(size_t)i * 288 + h * 24 + row16] = s[4 + r];
            if (row16 >= 8)
                opt_buf[(size_t)i * 288 + h * 24 + 8 + row16] = s[8 + r];
        }
    }
}

// ---------------------------------------------------------------------------
// Finalize: cat = [o(192) | x(96) | y(96) | z(96) | norm(96)]
// ---------------------------------------------------------------------------
__global__ __launch_bounds__(192) void finalize_kernel(
    const float* __restrict__ o_buf, const float* __restrict__ opt_buf,
    const float* __restrict__ Rd, const float* __restrict__ td,
    float* __restrict__ cat)
{
    const int i = blockIdx.x, t = threadIdx.x;
    cat[i * 576 + t] = o_buf[i * 192 + t];
    if (t < 96) {
        const float* op = opt_buf + i * 288 + t * 3;
        float x = op[0] - td[i * 3 + 0];
        float y = op[1] - td[i * 3 + 1];
        float z = op[2] - td[i * 3 + 2];
        const float* R = Rd + i * 9;
        float rx = R[0] * x + R[3] * y + R[6] * z;
        float ry = R[1] * x + R[4] * y + R[7] * z;
        float rz = R[2] * x + R[5] * y + R[8] * z;
        float* cc = cat + i * 576 + 192;
        cc[t] = rx;
        cc[96 + t] = ry;
        cc[192 + t] = rz;
        cc[288 + t] = sqrtf(rx * rx + ry * ry + rz * rz + 1e-8f);
    }
}

// ---------------------------------------------------------------------------
extern "C" void kernel_launch(void* const* d_in, const int* in_sizes, int n_in,
                              void* d_out, int out_size, void* d_ws, size_t ws_size,
                              hipStream_t stream)
{
    (void)in_sizes; (void)n_in; (void)out_size; (void)ws_size;
    const float* s_dst    = (const float*)d_in[0];
    const float* s_src    = (const float*)d_in[1];
    const float* R_dst    = (const float*)d_in[2];
    const float* t_dst    = (const float*)d_in[3];
    const float* R_src    = (const float*)d_in[4];
    const float* t_src    = (const float*)d_in[5];
    const float* dst_mask = (const float*)d_in[6];
    const float* src_mask = (const float*)d_in[7];
    const float* W_q      = (const float*)d_in[8];
    const float* W_kv     = (const float*)d_in[9];
    const float* W_qp     = (const float*)d_in[10];
    const float* W_kvp    = (const float*)d_in[11];
    const float* W_out    = (const float*)d_in[12];
    const float* b_out    = (const float*)d_in[13];
    const float* head_w   = (const float*)d_in[14];

    float* ws = (float*)d_ws;
    float* qcat    = ws;                    // 512*336    = 172032
    float* kvcat   = qcat    + 172032;      // 2048*816   = 1671168
    float* qp_rot  = kvcat   + 1671168;     // 512*144    = 73728
    float* sq_q    = qp_rot  + 73728;       // 512*12     = 6144
    float* o_buf   = sq_q    + 6144;        // 512*192    = 98304
    float* opt_buf = o_buf   + 98304;       // 512*288    = 147456
    float* cat_buf = opt_buf + 147456;      // 512*576    = 294912
    float* kT      = cat_buf + 294912;      // 12*16*2048 = 393216
    float* vAllT   = kT      + 393216;      // 12*40*2048 = 983040
    float* kpT     = vAllT   + 983040;      // 12*12*2048 = 294912
    float* sqkT    = kpT     + 294912;      // 12*2048    = 24576

    float* out_s    = (float*)d_out;              // 512*384
    float* out_a    = out_s    + 196608;          // 12*512*2048
    float* out_asd  = out_a    + 12582912;
    float* out_apts = out_asd  + 12582912;

    // Merged projection GEMMs, reading W directly (no transpose stage)
    proj_gemm_kernel<<<dim3(1840), dim3(64), 0, stream>>>(
        s_dst, s_src, W_q, W_qp, W_kv, W_kvp, qcat, kvcat);
    // Fused prep: rot_dst + rot_src + transpose_kv (coalesced writes)
    prep_kernel<<<dim3(32, 13), dim3(256), 0, stream>>>(
        qcat, kvcat, R_dst, t_dst, R_src, t_src,
        qp_rot, sq_q, kT, vAllT, kpT, sqkT);
    // Scores + softmax (+ a_sd, a_pts, a outputs)
    score_softmax_kernel<<<dim3(LD / 4, NH), dim3(256), 0, stream>>>(
        qcat, kT, qp_rot, kpT, sq_q, sqkT, dst_mask, src_mask, head_w,
        out_a, out_asd, out_apts);
    // MFMA AV: 8-wave blocks, K split across waves (8 x 256 = 2048), LDS reduce
    av_mfma_kernel<<<dim3(LD / 16, NH), dim3(512), 0, stream>>>(out_a, vAllT, o_buf, opt_buf);
    // Inverse rotation, norms, concat
    finalize_kernel<<<LD, 192, 0, stream>>>(o_buf, opt_buf, R_dst, t_dst, cat_buf);
    // Output projection, direct-W (+bias)
    out_gemm_kernel<<<dim3(16, 12), dim3(64), 0, stream>>>(cat_buf, W_out, b_out, out_s);
}